// Round 8
// baseline (841.167 us; speedup 1.0000x reference)
//
#include <hip/hip_runtime.h>
#include <hip/hip_cooperative_groups.h>
#include <math.h>

#define DEPTH 17
#define NNODES ((1 << DEPTH) - 1)
#define KTAIL 11  // levels k<=KTAIL run fused in one cooperative kernel

typedef _Float16 f16x8 __attribute__((ext_vector_type(8)));
typedef float f32x4 __attribute__((ext_vector_type(4)));

// [5/4] Pade tanh, clamped at |x|<=3.4: max err ~1.3e-3 (loose 1.7e-2 tol)
__device__ __forceinline__ float tanhP(float x) {
  float t = fminf(fmaxf(x, -3.4f), 3.4f);
  float s = t * t;
  float num = t * (945.0f + s * (105.0f + s));
  float den = 945.0f + s * (420.0f + 15.0f * s);
  return num * __builtin_amdgcn_rcpf(den);
}
__device__ __forceinline__ float sigP(float x) {
  return 0.5f + 0.5f * tanhP(0.5f * x);
}
__device__ __forceinline__ f16x8 pack8(const float4& a, const float4& b) {
  f16x8 r;
  r[0] = (_Float16)a.x; r[1] = (_Float16)a.y;
  r[2] = (_Float16)a.z; r[3] = (_Float16)a.w;
  r[4] = (_Float16)b.x; r[5] = (_Float16)b.y;
  r[6] = (_Float16)b.z; r[7] = (_Float16)b.w;
  return r;
}

// Lane-order-packed weights: for each (nb, w, g, cb) a 16x32 f16 tile stored
// so lane (q*16+l15) holds elems l15*32 + q*8 .. +7 -> one wave B-fragment =
// contiguous 1 KB, coalesced, L2-resident (1.97 MB total).
__global__ __launch_bounds__(256) void build_wb2(
    _Float16* __restrict__ Wb2, const float* __restrict__ W_iou,
    const float* __restrict__ U_iou, const float* __restrict__ U_f_w) {
  int idx = blockIdx.x * 256 + threadIdx.x;  // grid covers 1280*768 exactly
  int within = idx & 511;                    // l15*32 + kk
  int blk = idx >> 9;                        // ((nb*4+w)*5 + g)*24 + cb
  int l15 = within >> 5;
  int kk = within & 31;
  int cb = blk % 24;
  int t = blk / 24;
  int g = t % 5;
  int t2 = t / 5;
  int w = t2 & 3;
  int nb = t2 >> 2;
  int col = g * 256 + nb * 64 + w * 16 + l15;
  int k = cb * 32 + kk;
  float v;
  if (col < 768)
    v = (k < 256) ? W_iou[col * 256 + k] : U_iou[col * 512 + (k - 256)];
  else
    v = (k < 256) ? 0.0f : U_f_w[(col - 768) * 512 + (k - 256)];
  Wb2[idx] = (_Float16)v;
}

// Shared level body: fused GEMM (A[m,K] @ Wb^T) + TreeLSTM node apply.
// Main loop: A LDS double-buffered (reg-staged, dist-2 prefetch), B register
// ping-pong from lane-packed Wb2 (L2-resident). Epilogue: padded [64][68]
// f32 LDS tiles (stride 68 -> bank-conflict-free scatter-writes AND float4
// reads); c-inputs read direct-coalesced from global; Pade gates (no exp).
template <bool LEAF, bool H16, typename CT>
__device__ __forceinline__ void level_body(
    const float* __restrict__ x, const float* __restrict__ c0in,
    const _Float16* __restrict__ Wb2, const float* __restrict__ b_iou,
    const float* __restrict__ U_f_b, float* __restrict__ out,
    CT* __restrict__ cws, _Float16* __restrict__ hws, int m, int off,
    int coff, int r, int nb) {
  constexpr int NG = LEAF ? 3 : 5;    // gate groups of 64 output cols
  constexpr int NCH = LEAF ? 4 : 12;  // K / 64 (even)
  constexpr int NBU = NG * 2;         // B f16x8 fragments per chunk
  __shared__ __align__(16) char smem[34816];  // max(16K main, 2x[64][68]f32)
  f16x8* sA = (f16x8*)smem;

  const int tid = threadIdx.x;
  const int w = tid >> 6;
  const int lane = tid & 63;
  const int l15 = lane & 15;
  const int q = lane >> 4;
  const int pbase = r << 6;
  const int arow = tid >> 3;
  const int akc = tid & 7;

  auto LOADA = [&](float4 (&ax)[2][2], f16x8 (&ah)[2], int c) {
    const int k0 = (c << 6) + (akc << 3);
#pragma unroll
    for (int j = 0; j < 2; ++j) {
      const int row = arow + j * 32;
      const int p = pbase + row;
      const bool xpart = LEAF || c < 4;
      if (p < m) {
        if (xpart) {
          const float* src = x + (size_t)(off + p) * 256 + k0;
          ax[j][0] = *(const float4*)src;
          ax[j][1] = *(const float4*)(src + 4);
        } else if (H16) {
          ah[j] = *(const f16x8*)(hws + (size_t)(coff + 2 * p) * 256 +
                                  (k0 - 256));
        } else {
          const float* src = out + (size_t)(coff + 2 * p) * 256 + (k0 - 256);
          ax[j][0] = *(const float4*)src;
          ax[j][1] = *(const float4*)(src + 4);
        }
      } else {
        ax[j][0] = float4{0.f, 0.f, 0.f, 0.f};
        ax[j][1] = float4{0.f, 0.f, 0.f, 0.f};
        f16x8 z = {};
        ah[j] = z;
      }
    }
  };

  auto WRITEA = [&](float4 (&ax)[2][2], f16x8 (&ah)[2], int c) {
#pragma unroll
    for (int j = 0; j < 2; ++j) {
      const int row = arow + j * 32;
      f16x8 v;
      if (H16 && !LEAF && c >= 4) {
        v = ah[j];
      } else {
        v = pack8(ax[j][0], ax[j][1]);
      }
      sA[((c & 1) << 9) | (row << 3) | (akc ^ (row & 7))] = v;
    }
  };

  const _Float16* bb =
      Wb2 + (size_t)(nb * 4 + w) * (5 * 24 * 512) + l15 * 32 + q * 8;
  auto LOADB = [&](f16x8 (&bv)[NBU], int c) {
#pragma unroll
    for (int j = 0; j < NBU; ++j)
      bv[j] = *(const f16x8*)(bb + (((j >> 1) * 24 + c * 2 + (j & 1)) << 9));
  };

  f32x4 acc[NG][4] = {};

  auto COMPUTE = [&](int buf, f16x8 (&bv)[NBU]) {
    __builtin_amdgcn_s_setprio(1);
#pragma unroll
    for (int ks = 0; ks < 2; ++ks) {
      f16x8 af[4];
#pragma unroll
      for (int rf = 0; rf < 4; ++rf) {
        const int row = rf * 16 + l15;
        af[rf] = sA[(buf << 9) | (row << 3) | ((ks * 4 + q) ^ (row & 7))];
      }
#pragma unroll
      for (int g = 0; g < NG; ++g) {
        const f16x8 bf = bv[g * 2 + ks];
#pragma unroll
        for (int rf = 0; rf < 4; ++rf)
          acc[g][rf] = __builtin_amdgcn_mfma_f32_16x16x32_f16(
              af[rf], bf, acc[g][rf], 0, 0, 0);
      }
    }
    __builtin_amdgcn_s_setprio(0);
  };

  float4 axA[2][2], axB[2][2];
  f16x8 ahA[2], ahB[2];
  f16x8 bvA[NBU], bvB[NBU];

  LOADA(axA, ahA, 0);
  LOADB(bvA, 0);
  WRITEA(axA, ahA, 0);
  LOADA(axB, ahB, 1);
  LOADB(bvB, 1);
  __syncthreads();

  for (int c = 0; c < NCH; c += 2) {
    if (c + 2 < NCH) LOADA(axA, ahA, c + 2);
    COMPUTE(0, bvA);
    WRITEA(axB, ahB, c + 1);
    if (c + 2 < NCH) LOADB(bvA, c + 2);
    __syncthreads();
    if (c + 3 < NCH) LOADA(axB, ahB, c + 3);
    COMPUTE(1, bvB);
    if (c + 2 < NCH) {
      WRITEA(axA, ahA, c + 2);
      if (c + 3 < NCH) LOADB(bvB, c + 3);
      __syncthreads();
    }
  }
  __syncthreads();  // main loop done; smem free for epilogue

  // ===== epilogue: padded-tile transpose, all global I/O coalesced ========
  const int erow = tid >> 2;           // 0..63 (row-layout row)
  const int eseg = tid & 3;            // 16-float window
  const int p_e = pbase + erow;
  const bool pv = p_e < m;
  float* T0 = (float*)smem;            // [64][68] f32
  float* T1 = T0 + 64 * 68;
  const int scol = (w << 4) + l15;     // scatter col (acc layout)
  const int n = (nb << 6) + scol;
  const int rbase = erow * 68 + (eseg << 4);

  float cred[16];
  if constexpr (!LEAF) {
    // early coalesced child-c loads (hide under E2a scatter + sync)
    float c0v[16], c1v[16];
    if (pv) {
      const CT* csrc =
          cws + (size_t)(coff + 2 * p_e) * 256 + (nb << 6) + (eseg << 4);
      if constexpr (sizeof(CT) == 2) {
        f16x8 a0 = *(const f16x8*)csrc;
        f16x8 a1 = *(const f16x8*)(csrc + 8);
        f16x8 b0 = *(const f16x8*)(csrc + 256);
        f16x8 b1 = *(const f16x8*)(csrc + 264);
#pragma unroll
        for (int j = 0; j < 8; ++j) {
          c0v[j] = (float)a0[j]; c0v[8 + j] = (float)a1[j];
          c1v[j] = (float)b0[j]; c1v[8 + j] = (float)b1[j];
        }
      } else {
#pragma unroll
        for (int jj = 0; jj < 4; ++jj) {
          float4 v0 = *(const float4*)((const float*)csrc + jj * 4);
          float4 v1 = *(const float4*)((const float*)csrc + 256 + jj * 4);
          c0v[jj * 4 + 0] = v0.x; c0v[jj * 4 + 1] = v0.y;
          c0v[jj * 4 + 2] = v0.z; c0v[jj * 4 + 3] = v0.w;
          c1v[jj * 4 + 0] = v1.x; c1v[jj * 4 + 1] = v1.y;
          c1v[jj * 4 + 2] = v1.z; c1v[jj * 4 + 3] = v1.w;
        }
      }
    } else {
#pragma unroll
      for (int j = 0; j < 16; ++j) { c0v[j] = 0.f; c1v[j] = 0.f; }
    }
    // E2a: scatter f0,f1 (b32 writes, 2-way max = free with stride 68)
    const float bf0 = U_f_b[n], bf1 = U_f_b[256 + n];
#pragma unroll
    for (int rf = 0; rf < 4; ++rf)
#pragma unroll
      for (int rr = 0; rr < 4; ++rr) {
        const int prow = rf * 16 + (q << 2) + rr;
        T0[prow * 68 + scol] = sigP(acc[3][rf][rr] + bf0);
        T1[prow * 68 + scol] = sigP(acc[4][rf][rr] + bf1);
      }
    __syncthreads();
    // E2b: cred in row layout (coalesced float4 tile reads)
#pragma unroll
    for (int jj = 0; jj < 4; ++jj) {
      float4 f04 = *(const float4*)&T0[rbase + jj * 4];
      float4 f14 = *(const float4*)&T1[rbase + jj * 4];
      cred[jj * 4 + 0] = f04.x * c0v[jj * 4 + 0] + f14.x * c1v[jj * 4 + 0];
      cred[jj * 4 + 1] = f04.y * c0v[jj * 4 + 1] + f14.y * c1v[jj * 4 + 1];
      cred[jj * 4 + 2] = f04.z * c0v[jj * 4 + 2] + f14.z * c1v[jj * 4 + 2];
      cred[jj * 4 + 3] = f04.w * c0v[jj * 4 + 3] + f14.w * c1v[jj * 4 + 3];
    }
    __syncthreads();
  } else {
    // leaf: cred = c0, direct coalesced global read
    if (pv) {
      const float* src =
          c0in + (size_t)(off + p_e) * 256 + (nb << 6) + (eseg << 4);
#pragma unroll
      for (int jj = 0; jj < 4; ++jj) {
        float4 v = *(const float4*)(src + jj * 4);
        cred[jj * 4 + 0] = v.x; cred[jj * 4 + 1] = v.y;
        cred[jj * 4 + 2] = v.z; cred[jj * 4 + 3] = v.w;
      }
    } else {
#pragma unroll
      for (int j = 0; j < 16; ++j) cred[j] = 0.f;
    }
  }

  // E2c: scatter iu, o
  {
    const float bi = b_iou[n], bo = b_iou[256 + n], bu = b_iou[512 + n];
#pragma unroll
    for (int rf = 0; rf < 4; ++rf)
#pragma unroll
      for (int rr = 0; rr < 4; ++rr) {
        const int prow = rf * 16 + (q << 2) + rr;
        const float iv = sigP(acc[0][rf][rr] + bi);
        const float uv = tanhP(acc[2][rf][rr] + bu);
        const float ov = sigP(acc[1][rf][rr] + bo);
        T0[prow * 68 + scol] = iv * uv;
        T1[prow * 68 + scol] = ov;
      }
  }
  __syncthreads();

  // E2d: combine + coalesced vector stores
  if (pv) {
    float4 h4[4], c4[4];
#pragma unroll
    for (int jj = 0; jj < 4; ++jj) {
      float4 iu4 = *(const float4*)&T0[rbase + jj * 4];
      float4 o4 = *(const float4*)&T1[rbase + jj * 4];
      float cc;
      cc = iu4.x + cred[jj * 4 + 0]; c4[jj].x = cc; h4[jj].x = o4.x * tanhP(cc);
      cc = iu4.y + cred[jj * 4 + 1]; c4[jj].y = cc; h4[jj].y = o4.y * tanhP(cc);
      cc = iu4.z + cred[jj * 4 + 2]; c4[jj].z = cc; h4[jj].z = o4.z * tanhP(cc);
      cc = iu4.w + cred[jj * 4 + 3]; c4[jj].w = cc; h4[jj].w = o4.w * tanhP(cc);
    }
    const size_t ob = (size_t)(off + p_e) * 256 + (nb << 6) + (eseg << 4);
    float* dst = out + ob;
#pragma unroll
    for (int jj = 0; jj < 4; ++jj) *(float4*)(dst + jj * 4) = h4[jj];
    if constexpr (H16) {
      *(f16x8*)(hws + ob) = pack8(h4[0], h4[1]);
      *(f16x8*)(hws + ob + 8) = pack8(h4[2], h4[3]);
    }
    if constexpr (sizeof(CT) == 2) {
      *(f16x8*)((_Float16*)cws + ob) = pack8(c4[0], c4[1]);
      *(f16x8*)((_Float16*)cws + ob + 8) = pack8(c4[2], c4[3]);
    } else {
      float* cdst = (float*)cws + ob;
#pragma unroll
      for (int jj = 0; jj < 4; ++jj) *(float4*)(cdst + jj * 4) = c4[jj];
    }
  }
}

template <bool LEAF, bool H16, typename CT>
__global__ __launch_bounds__(256, 2) void level_kernel(
    const float* __restrict__ x, const float* __restrict__ c0in,
    const _Float16* __restrict__ Wb2, const float* __restrict__ b_iou,
    const float* __restrict__ U_f_b, float* __restrict__ out,
    CT* __restrict__ cws, _Float16* __restrict__ hws, int m, int off,
    int coff) {
  int bx = blockIdx.x, r, nb;
  if ((gridDim.x & 31) == 0) {  // XCD-grouped: nb-splits share bid%8
    nb = (bx >> 3) & 3;
    r = ((bx >> 5) << 3) + (bx & 7);
  } else {
    r = bx >> 2;
    nb = bx & 3;
  }
  level_body<LEAF, H16, CT>(x, c0in, Wb2, b_iou, U_f_b, out, cws, hws, m, off,
                            coff, r, nb);
}

// Fused top-of-tree: levels KTAIL..0 in one cooperative kernel, grid.sync
// between levels. Grid = 4 * ceil(2^KTAIL / 64) blocks.
template <bool H16, typename CT>
__global__ __launch_bounds__(256, 2) void tail_kernel(
    const float* __restrict__ x, const float* __restrict__ c0in,
    const _Float16* __restrict__ Wb2, const float* __restrict__ b_iou,
    const float* __restrict__ U_f_b, float* __restrict__ out,
    CT* __restrict__ cws, _Float16* __restrict__ hws) {
  cooperative_groups::grid_group grid = cooperative_groups::this_grid();
  for (int k = KTAIL; k >= 0; --k) {
    const int m = 1 << k;
    const int R = (m + 63) >> 6;
    if ((int)blockIdx.x < R * 4) {
      level_body<false, H16, CT>(x, c0in, Wb2, b_iou, U_f_b, out, cws, hws, m,
                                 m - 1, 2 * m - 1, blockIdx.x >> 2,
                                 blockIdx.x & 3);
    }
    grid.sync();
  }
}

template <bool H16, typename CT>
static void run_levels(const float* x, const float* c0, const _Float16* Wb2,
                       const float* b_iou, const float* U_f_b, float* out,
                       CT* cws, _Float16* hws, hipStream_t stream) {
  level_kernel<true, H16, CT><<<dim3(4096), 256, 0, stream>>>(
      x, c0, Wb2, b_iou, U_f_b, out, cws, hws, 65536, 65535, 0);
  for (int k = DEPTH - 2; k > KTAIL; --k) {
    const int m = 1 << k;
    level_kernel<false, H16, CT><<<dim3((m / 64) * 4), 256, 0, stream>>>(
        x, c0, Wb2, b_iou, U_f_b, out, cws, hws, m, m - 1, 2 * m - 1);
  }
  // fused tail (cooperative); per-level fallback if the launch is rejected
  {
    const int tgrid = 4 * ((1 << KTAIL) / 64);  // 128
    void* args[] = {(void*)&x,     (void*)&c0,  (void*)&Wb2,
                    (void*)&b_iou, (void*)&U_f_b, (void*)&out,
                    (void*)&cws,   (void*)&hws};
    hipError_t e = hipLaunchCooperativeKernel(tail_kernel<H16, CT>,
                                              dim3(tgrid), dim3(256), args, 0,
                                              stream);
    if (e != hipSuccess) {
      for (int k = KTAIL; k >= 0; --k) {
        const int m = 1 << k;
        const int R = (m + 63) / 64;
        level_kernel<false, H16, CT><<<dim3(R * 4), 256, 0, stream>>>(
            x, c0, Wb2, b_iou, U_f_b, out, cws, hws, m, m - 1, 2 * m - 1);
      }
    }
  }
}

extern "C" void kernel_launch(void* const* d_in, const int* in_sizes, int n_in,
                              void* d_out, int out_size, void* d_ws, size_t ws_size,
                              hipStream_t stream) {
  const float* x     = (const float*)d_in[0];
  // d_in[1] = h0 (unused by the reference's math)
  const float* c0    = (const float*)d_in[2];
  const float* W_iou = (const float*)d_in[3];
  const float* U_iou = (const float*)d_in[4];
  const float* b_iou = (const float*)d_in[5];
  const float* U_f_w = (const float*)d_in[6];
  const float* U_f_b = (const float*)d_in[7];
  float* out = (float*)d_out;

  char* ws = (char*)d_ws;
  const size_t wbBytes = (size_t)1280 * 768 * 2;  // 1.97 MB, 16B-aligned
  _Float16* Wb2 = (_Float16*)ws;
  build_wb2<<<3840, 256, 0, stream>>>(Wb2, W_iou, U_iou, U_f_w);

  const size_t cElems = (size_t)NNODES * 256;
  char* p1 = ws + wbBytes;
  if (ws_size >= wbBytes + cElems * 2 + cElems * 2) {
    // c in f16 (halved traffic) + h mirrored in f16 for the parent GEMM
    run_levels<true, _Float16>(x, c0, Wb2, b_iou, U_f_b, out, (_Float16*)p1,
                               (_Float16*)(p1 + cElems * 2), stream);
  } else if (ws_size >= wbBytes + cElems * 4) {
    run_levels<false, float>(x, c0, Wb2, b_iou, U_f_b, out, (float*)p1,
                             nullptr, stream);
  } else {
    run_levels<false, _Float16>(x, c0, Wb2, b_iou, U_f_b, out, (_Float16*)p1,
                                nullptr, stream);
  }
}

// Round 9
// 817.546 us; speedup vs baseline: 1.0289x; 1.0289x over previous
//
#include <hip/hip_runtime.h>
#include <math.h>

#define DEPTH 17
#define NNODES ((1 << DEPTH) - 1)

typedef _Float16 f16x8 __attribute__((ext_vector_type(8)));
typedef float f32x4 __attribute__((ext_vector_type(4)));

// [5/4] Pade tanh, clamped at |x|<=3.4: max err ~1.3e-3 (loose 1.7e-2 tol)
__device__ __forceinline__ float tanhP(float x) {
  float t = fminf(fmaxf(x, -3.4f), 3.4f);
  float s = t * t;
  float num = t * (945.0f + s * (105.0f + s));
  float den = 945.0f + s * (420.0f + 15.0f * s);
  return num * __builtin_amdgcn_rcpf(den);
}
__device__ __forceinline__ float sigP(float x) {
  return 0.5f + 0.5f * tanhP(0.5f * x);
}
__device__ __forceinline__ f16x8 pack8(const float4& a, const float4& b) {
  f16x8 r;
  r[0] = (_Float16)a.x; r[1] = (_Float16)a.y;
  r[2] = (_Float16)a.z; r[3] = (_Float16)a.w;
  r[4] = (_Float16)b.x; r[5] = (_Float16)b.y;
  r[6] = (_Float16)b.z; r[7] = (_Float16)b.w;
  return r;
}

// Lane-order-packed weights: for each (nb, w, g, cb) a 16x32 f16 tile stored
// so lane (q*16+l15) holds elems l15*32 + q*8 .. +7 -> one wave B-fragment =
// contiguous 1 KB, coalesced, L2-resident (1.97 MB total).
__global__ __launch_bounds__(256) void build_wb2(
    _Float16* __restrict__ Wb2, const float* __restrict__ W_iou,
    const float* __restrict__ U_iou, const float* __restrict__ U_f_w) {
  int idx = blockIdx.x * 256 + threadIdx.x;  // grid covers 1280*768 exactly
  int within = idx & 511;                    // l15*32 + kk
  int blk = idx >> 9;                        // ((nb*4+w)*5 + g)*24 + cb
  int l15 = within >> 5;
  int kk = within & 31;
  int cb = blk % 24;
  int t = blk / 24;
  int g = t % 5;
  int t2 = t / 5;
  int w = t2 & 3;
  int nb = t2 >> 2;
  int col = g * 256 + nb * 64 + w * 16 + l15;
  int k = cb * 32 + kk;
  float v;
  if (col < 768)
    v = (k < 256) ? W_iou[col * 256 + k] : U_iou[col * 512 + (k - 256)];
  else
    v = (k < 256) ? 0.0f : U_f_w[(col - 768) * 512 + (k - 256)];
  Wb2[idx] = (_Float16)v;
}

// ======================= big-level body (unchanged R8) ======================
template <bool LEAF, bool H16, typename CT>
__device__ __forceinline__ void level_body(
    const float* __restrict__ x, const float* __restrict__ c0in,
    const _Float16* __restrict__ Wb2, const float* __restrict__ b_iou,
    const float* __restrict__ U_f_b, float* __restrict__ out,
    CT* __restrict__ cws, _Float16* __restrict__ hws, int m, int off,
    int coff, int r, int nb) {
  constexpr int NG = LEAF ? 3 : 5;    // gate groups of 64 output cols
  constexpr int NCH = LEAF ? 4 : 12;  // K / 64 (even)
  constexpr int NBU = NG * 2;         // B f16x8 fragments per chunk
  __shared__ __align__(16) char smem[34816];  // max(16K main, 2x[64][68]f32)
  f16x8* sA = (f16x8*)smem;

  const int tid = threadIdx.x;
  const int w = tid >> 6;
  const int lane = tid & 63;
  const int l15 = lane & 15;
  const int q = lane >> 4;
  const int pbase = r << 6;
  const int arow = tid >> 3;
  const int akc = tid & 7;

  auto LOADA = [&](float4 (&ax)[2][2], f16x8 (&ah)[2], int c) {
    const int k0 = (c << 6) + (akc << 3);
#pragma unroll
    for (int j = 0; j < 2; ++j) {
      const int row = arow + j * 32;
      const int p = pbase + row;
      const bool xpart = LEAF || c < 4;
      if (p < m) {
        if (xpart) {
          const float* src = x + (size_t)(off + p) * 256 + k0;
          ax[j][0] = *(const float4*)src;
          ax[j][1] = *(const float4*)(src + 4);
        } else if (H16) {
          ah[j] = *(const f16x8*)(hws + (size_t)(coff + 2 * p) * 256 +
                                  (k0 - 256));
        } else {
          const float* src = out + (size_t)(coff + 2 * p) * 256 + (k0 - 256);
          ax[j][0] = *(const float4*)src;
          ax[j][1] = *(const float4*)(src + 4);
        }
      } else {
        ax[j][0] = float4{0.f, 0.f, 0.f, 0.f};
        ax[j][1] = float4{0.f, 0.f, 0.f, 0.f};
        f16x8 z = {};
        ah[j] = z;
      }
    }
  };

  auto WRITEA = [&](float4 (&ax)[2][2], f16x8 (&ah)[2], int c) {
#pragma unroll
    for (int j = 0; j < 2; ++j) {
      const int row = arow + j * 32;
      f16x8 v;
      if (H16 && !LEAF && c >= 4) {
        v = ah[j];
      } else {
        v = pack8(ax[j][0], ax[j][1]);
      }
      sA[((c & 1) << 9) | (row << 3) | (akc ^ (row & 7))] = v;
    }
  };

  const _Float16* bb =
      Wb2 + (size_t)(nb * 4 + w) * (5 * 24 * 512) + l15 * 32 + q * 8;
  auto LOADB = [&](f16x8 (&bv)[NBU], int c) {
#pragma unroll
    for (int j = 0; j < NBU; ++j)
      bv[j] = *(const f16x8*)(bb + (((j >> 1) * 24 + c * 2 + (j & 1)) << 9));
  };

  f32x4 acc[NG][4] = {};

  auto COMPUTE = [&](int buf, f16x8 (&bv)[NBU]) {
    __builtin_amdgcn_s_setprio(1);
#pragma unroll
    for (int ks = 0; ks < 2; ++ks) {
      f16x8 af[4];
#pragma unroll
      for (int rf = 0; rf < 4; ++rf) {
        const int row = rf * 16 + l15;
        af[rf] = sA[(buf << 9) | (row << 3) | ((ks * 4 + q) ^ (row & 7))];
      }
#pragma unroll
      for (int g = 0; g < NG; ++g) {
        const f16x8 bf = bv[g * 2 + ks];
#pragma unroll
        for (int rf = 0; rf < 4; ++rf)
          acc[g][rf] = __builtin_amdgcn_mfma_f32_16x16x32_f16(
              af[rf], bf, acc[g][rf], 0, 0, 0);
      }
    }
    __builtin_amdgcn_s_setprio(0);
  };

  float4 axA[2][2], axB[2][2];
  f16x8 ahA[2], ahB[2];
  f16x8 bvA[NBU], bvB[NBU];

  LOADA(axA, ahA, 0);
  LOADB(bvA, 0);
  WRITEA(axA, ahA, 0);
  LOADA(axB, ahB, 1);
  LOADB(bvB, 1);
  __syncthreads();

  for (int c = 0; c < NCH; c += 2) {
    if (c + 2 < NCH) LOADA(axA, ahA, c + 2);
    COMPUTE(0, bvA);
    WRITEA(axB, ahB, c + 1);
    if (c + 2 < NCH) LOADB(bvA, c + 2);
    __syncthreads();
    if (c + 3 < NCH) LOADA(axB, ahB, c + 3);
    COMPUTE(1, bvB);
    if (c + 2 < NCH) {
      WRITEA(axA, ahA, c + 2);
      if (c + 3 < NCH) LOADB(bvB, c + 3);
      __syncthreads();
    }
  }
  __syncthreads();  // main loop done; smem free for epilogue

  // ===== epilogue: padded-tile transpose, all global I/O coalesced ========
  const int erow = tid >> 2;
  const int eseg = tid & 3;
  const int p_e = pbase + erow;
  const bool pv = p_e < m;
  float* T0 = (float*)smem;            // [64][68] f32
  float* T1 = T0 + 64 * 68;
  const int scol = (w << 4) + l15;
  const int n = (nb << 6) + scol;
  const int rbase = erow * 68 + (eseg << 4);

  float cred[16];
  if constexpr (!LEAF) {
    float c0v[16], c1v[16];
    if (pv) {
      const CT* csrc =
          cws + (size_t)(coff + 2 * p_e) * 256 + (nb << 6) + (eseg << 4);
      if constexpr (sizeof(CT) == 2) {
        f16x8 a0 = *(const f16x8*)csrc;
        f16x8 a1 = *(const f16x8*)(csrc + 8);
        f16x8 b0 = *(const f16x8*)(csrc + 256);
        f16x8 b1 = *(const f16x8*)(csrc + 264);
#pragma unroll
        for (int j = 0; j < 8; ++j) {
          c0v[j] = (float)a0[j]; c0v[8 + j] = (float)a1[j];
          c1v[j] = (float)b0[j]; c1v[8 + j] = (float)b1[j];
        }
      } else {
#pragma unroll
        for (int jj = 0; jj < 4; ++jj) {
          float4 v0 = *(const float4*)((const float*)csrc + jj * 4);
          float4 v1 = *(const float4*)((const float*)csrc + 256 + jj * 4);
          c0v[jj * 4 + 0] = v0.x; c0v[jj * 4 + 1] = v0.y;
          c0v[jj * 4 + 2] = v0.z; c0v[jj * 4 + 3] = v0.w;
          c1v[jj * 4 + 0] = v1.x; c1v[jj * 4 + 1] = v1.y;
          c1v[jj * 4 + 2] = v1.z; c1v[jj * 4 + 3] = v1.w;
        }
      }
    } else {
#pragma unroll
      for (int j = 0; j < 16; ++j) { c0v[j] = 0.f; c1v[j] = 0.f; }
    }
    const float bf0 = U_f_b[n], bf1 = U_f_b[256 + n];
#pragma unroll
    for (int rf = 0; rf < 4; ++rf)
#pragma unroll
      for (int rr = 0; rr < 4; ++rr) {
        const int prow = rf * 16 + (q << 2) + rr;
        T0[prow * 68 + scol] = sigP(acc[3][rf][rr] + bf0);
        T1[prow * 68 + scol] = sigP(acc[4][rf][rr] + bf1);
      }
    __syncthreads();
#pragma unroll
    for (int jj = 0; jj < 4; ++jj) {
      float4 f04 = *(const float4*)&T0[rbase + jj * 4];
      float4 f14 = *(const float4*)&T1[rbase + jj * 4];
      cred[jj * 4 + 0] = f04.x * c0v[jj * 4 + 0] + f14.x * c1v[jj * 4 + 0];
      cred[jj * 4 + 1] = f04.y * c0v[jj * 4 + 1] + f14.y * c1v[jj * 4 + 1];
      cred[jj * 4 + 2] = f04.z * c0v[jj * 4 + 2] + f14.z * c1v[jj * 4 + 2];
      cred[jj * 4 + 3] = f04.w * c0v[jj * 4 + 3] + f14.w * c1v[jj * 4 + 3];
    }
    __syncthreads();
  } else {
    if (pv) {
      const float* src =
          c0in + (size_t)(off + p_e) * 256 + (nb << 6) + (eseg << 4);
#pragma unroll
      for (int jj = 0; jj < 4; ++jj) {
        float4 v = *(const float4*)(src + jj * 4);
        cred[jj * 4 + 0] = v.x; cred[jj * 4 + 1] = v.y;
        cred[jj * 4 + 2] = v.z; cred[jj * 4 + 3] = v.w;
      }
    } else {
#pragma unroll
      for (int j = 0; j < 16; ++j) cred[j] = 0.f;
    }
  }

  {
    const float bi = b_iou[n], bo = b_iou[256 + n], bu = b_iou[512 + n];
#pragma unroll
    for (int rf = 0; rf < 4; ++rf)
#pragma unroll
      for (int rr = 0; rr < 4; ++rr) {
        const int prow = rf * 16 + (q << 2) + rr;
        const float iv = sigP(acc[0][rf][rr] + bi);
        const float uv = tanhP(acc[2][rf][rr] + bu);
        const float ov = sigP(acc[1][rf][rr] + bo);
        T0[prow * 68 + scol] = iv * uv;
        T1[prow * 68 + scol] = ov;
      }
  }
  __syncthreads();

  if (pv) {
    float4 h4[4], c4[4];
#pragma unroll
    for (int jj = 0; jj < 4; ++jj) {
      float4 iu4 = *(const float4*)&T0[rbase + jj * 4];
      float4 o4 = *(const float4*)&T1[rbase + jj * 4];
      float cc;
      cc = iu4.x + cred[jj * 4 + 0]; c4[jj].x = cc; h4[jj].x = o4.x * tanhP(cc);
      cc = iu4.y + cred[jj * 4 + 1]; c4[jj].y = cc; h4[jj].y = o4.y * tanhP(cc);
      cc = iu4.z + cred[jj * 4 + 2]; c4[jj].z = cc; h4[jj].z = o4.z * tanhP(cc);
      cc = iu4.w + cred[jj * 4 + 3]; c4[jj].w = cc; h4[jj].w = o4.w * tanhP(cc);
    }
    const size_t ob = (size_t)(off + p_e) * 256 + (nb << 6) + (eseg << 4);
    float* dst = out + ob;
#pragma unroll
    for (int jj = 0; jj < 4; ++jj) *(float4*)(dst + jj * 4) = h4[jj];
    if constexpr (H16) {
      *(f16x8*)(hws + ob) = pack8(h4[0], h4[1]);
      *(f16x8*)(hws + ob + 8) = pack8(h4[2], h4[3]);
    }
    if constexpr (sizeof(CT) == 2) {
      *(f16x8*)((_Float16*)cws + ob) = pack8(c4[0], c4[1]);
      *(f16x8*)((_Float16*)cws + ob + 8) = pack8(c4[2], c4[3]);
    } else {
      float* cdst = (float*)cws + ob;
#pragma unroll
      for (int jj = 0; jj < 4; ++jj) *(float4*)(cdst + jj * 4) = c4[jj];
    }
  }
}

template <bool LEAF, bool H16, typename CT>
__global__ __launch_bounds__(256, 2) void level_kernel(
    const float* __restrict__ x, const float* __restrict__ c0in,
    const _Float16* __restrict__ Wb2, const float* __restrict__ b_iou,
    const float* __restrict__ U_f_b, float* __restrict__ out,
    CT* __restrict__ cws, _Float16* __restrict__ hws, int m, int off,
    int coff) {
  int bx = blockIdx.x, r, nb;
  if ((gridDim.x & 31) == 0) {  // XCD-grouped: nb-splits share bid%8
    nb = (bx >> 3) & 3;
    r = ((bx >> 5) << 3) + (bx & 7);
  } else {
    r = bx >> 2;
    nb = bx & 3;
  }
  level_body<LEAF, H16, CT>(x, c0in, Wb2, b_iou, U_f_b, out, cws, hws, m, off,
                            coff, r, nb);
}

// ================== subtree tail: block-local LDS recurrence ===============
// hslot: 16B-unit slot for LDS h/c tiles, XOR-swizzled so that K-loop
// fragment reads (node = 2*(rf*16+l15)+child) are <=2-way bank aliased.
__device__ __forceinline__ int hslot(int node, int u) {
  return node * 32 + (u ^ (((node >> 1) & 15) << 1));
}

template <int RF, bool FIRST>
__device__ __forceinline__ void tail_level(
    const float* __restrict__ x, const _Float16* __restrict__ Wb2,
    const float* __restrict__ b_iou, const float* __restrict__ U_f_b,
    float* __restrict__ out, _Float16* __restrict__ hws,
    _Float16* __restrict__ cws, const _Float16* hprev, const _Float16* cprev,
    _Float16* hcur, _Float16* ccur, int m_local, int lvl_off, int choff,
    int nbase, bool wg16) {
  const int tid = threadIdx.x;
  const int w = tid >> 6;
  const int lane = tid & 63;
  const int l15 = lane & 15;
  const int q = lane >> 4;

#pragma unroll 1
  for (int nb = 0; nb < 4; ++nb) {
    const _Float16* bb =
        Wb2 + (size_t)(nb * 4 + w) * (5 * 24 * 512) + l15 * 32 + q * 8;
    f16x8 bv0[10], bv1[10];
#pragma unroll
    for (int j = 0; j < 10; ++j)
      bv0[j] = *(const f16x8*)(bb + (((j >> 1) * 24 + (j & 1)) << 9));
    f32x4 acc[5][RF] = {};

#pragma unroll
    for (int c = 0; c < 12; ++c) {
      f16x8* bvc = (c & 1) ? bv1 : bv0;
      f16x8* bvn = (c & 1) ? bv0 : bv1;
      if (c + 1 < 12) {
#pragma unroll
        for (int j = 0; j < 10; ++j)
          bvn[j] = *(const f16x8*)(
              bb + (((j >> 1) * 24 + (c + 1) * 2 + (j & 1)) << 9));
      }
      f16x8 af[2][RF];
#pragma unroll
      for (int ks = 0; ks < 2; ++ks)
#pragma unroll
        for (int rf = 0; rf < RF; ++rf) {
          const int row = rf * 16 + l15;
          const int rowc = row < m_local ? row : 0;
          if (c < 4) {
            const float* src = x + (size_t)(lvl_off + nbase + rowc) * 256 +
                               (c << 6) + (ks * 4 + q) * 8;
            float4 a0 = *(const float4*)src;
            float4 a1 = *(const float4*)(src + 4);
            af[ks][rf] = pack8(a0, a1);
          } else {
            const int kk = ((c - 4) << 6) + (ks * 4 + q) * 8;
            const int child = kk >> 8, off = kk & 255;
            if (FIRST) {
              af[ks][rf] = *(const f16x8*)(
                  hws + (size_t)(choff + 2 * (nbase + rowc) + child) * 256 +
                  off);
            } else {
              af[ks][rf] =
                  *(const f16x8*)&hprev[hslot(2 * rowc + child, off >> 3) * 8];
            }
          }
        }
#pragma unroll
      for (int ks = 0; ks < 2; ++ks)
#pragma unroll
        for (int g = 0; g < 5; ++g)
#pragma unroll
          for (int rf = 0; rf < RF; ++rf)
            acc[g][rf] = __builtin_amdgcn_mfma_f32_16x16x32_f16(
                af[ks][rf], bvc[g * 2 + ks], acc[g][rf], 0, 0, 0);
    }

    // quarter epilogue: acc-layout scalar (tiny volume; latency-tolerant)
    const int n = (nb << 6) + (w << 4) + l15;
    const float bi = b_iou[n], bo = b_iou[256 + n], bu = b_iou[512 + n];
    const float bf0 = U_f_b[n], bf1 = U_f_b[256 + n];
#pragma unroll
    for (int rf = 0; rf < RF; ++rf)
#pragma unroll
      for (int rr = 0; rr < 4; ++rr) {
        const int prow = rf * 16 + (q << 2) + rr;
        if (prow < m_local) {
          float c0v, c1v;
          if (FIRST) {
            c0v = (float)cws[(size_t)(choff + 2 * (nbase + prow)) * 256 + n];
            c1v =
                (float)cws[(size_t)(choff + 2 * (nbase + prow) + 1) * 256 + n];
          } else {
            c0v = (float)cprev[hslot(2 * prow, n >> 3) * 8 + (n & 7)];
            c1v = (float)cprev[hslot(2 * prow + 1, n >> 3) * 8 + (n & 7)];
          }
          const float f0 = sigP(acc[3][rf][rr] + bf0);
          const float f1 = sigP(acc[4][rf][rr] + bf1);
          const float iv = sigP(acc[0][rf][rr] + bi);
          const float uv = tanhP(acc[2][rf][rr] + bu);
          const float ov = sigP(acc[1][rf][rr] + bo);
          const float cc = iv * uv + f0 * c0v + f1 * c1v;
          const float hh = ov * tanhP(cc);
          const size_t gn = (size_t)(lvl_off + nbase + prow) * 256 + n;
          out[gn] = hh;
          if (wg16) {
            hws[gn] = (_Float16)hh;
            cws[gn] = (_Float16)cc;
          }
          hcur[hslot(prow, n >> 3) * 8 + (n & 7)] = (_Float16)hh;
          ccur[hslot(prow, n >> 3) * 8 + (n & 7)] = (_Float16)cc;
        }
      }
  }
}

// 6 levels from firstK down; each block = an independent 32-wide subtree.
// h/c flow between levels through LDS (f16, ping-pong); one __syncthreads
// per level. First level reads children from global hws/cws (previous
// dispatch); WG16 mirrors outputs to hws/cws (needed for the T1->T2 handoff).
template <bool WG16>
__global__ __launch_bounds__(256, 1) void tail_kernel(
    const float* __restrict__ x, const _Float16* __restrict__ Wb2,
    const float* __restrict__ b_iou, const float* __restrict__ U_f_b,
    float* __restrict__ out, _Float16* __restrict__ hws,
    _Float16* __restrict__ cws, int firstK) {
  __shared__ _Float16 hA[32 * 256], cA[32 * 256];  // 16 KB each
  __shared__ _Float16 hB[16 * 256], cB[16 * 256];  // 8 KB each
  const int b = blockIdx.x;
#pragma unroll 1
  for (int d = 0; d < 6; ++d) {
    const int k = firstK - d;
    const int m_local = 32 >> d;
    const int lvl_off = (1 << k) - 1;
    const int choff = (1 << (k + 1)) - 1;
    const int nbase = m_local * b;
    _Float16* hc = (d & 1) ? hB : hA;
    _Float16* cc_ = (d & 1) ? cB : cA;
    _Float16* hp = (d & 1) ? hA : hB;
    _Float16* cp = (d & 1) ? cA : cB;
    if (d == 0)
      tail_level<2, true>(x, Wb2, b_iou, U_f_b, out, hws, cws, nullptr,
                          nullptr, hc, cc_, m_local, lvl_off, choff, nbase,
                          WG16);
    else
      tail_level<1, false>(x, Wb2, b_iou, U_f_b, out, hws, cws, hp, cp, hc,
                           cc_, m_local, lvl_off, choff, nbase, WG16);
    __syncthreads();
  }
}

// ============================== dispatch ===================================
template <bool H16, typename CT>
static void run_levels(const float* x, const float* c0, const _Float16* Wb2,
                       const float* b_iou, const float* U_f_b, float* out,
                       CT* cws, _Float16* hws, hipStream_t stream) {
  level_kernel<true, H16, CT><<<dim3(4096), 256, 0, stream>>>(
      x, c0, Wb2, b_iou, U_f_b, out, cws, hws, 65536, 65535, 0);
  constexpr bool TAIL_OK = H16 && sizeof(CT) == 2;
  const int kmin = TAIL_OK ? 12 : 0;
  for (int k = DEPTH - 2; k >= kmin; --k) {
    const int m = 1 << k;
    const int R = (m + 63) / 64;
    level_kernel<false, H16, CT><<<dim3(R * 4), 256, 0, stream>>>(
        x, c0, Wb2, b_iou, U_f_b, out, cws, hws, m, m - 1, 2 * m - 1);
  }
  if constexpr (TAIL_OK) {
    // levels 11..6: 64 independent subtrees; levels 5..0: one subtree
    tail_kernel<true><<<dim3(64), 256, 0, stream>>>(
        x, Wb2, b_iou, U_f_b, out, hws, (_Float16*)cws, 11);
    tail_kernel<false><<<dim3(1), 256, 0, stream>>>(
        x, Wb2, b_iou, U_f_b, out, hws, (_Float16*)cws, 5);
  }
}

extern "C" void kernel_launch(void* const* d_in, const int* in_sizes, int n_in,
                              void* d_out, int out_size, void* d_ws, size_t ws_size,
                              hipStream_t stream) {
  const float* x     = (const float*)d_in[0];
  // d_in[1] = h0 (unused by the reference's math)
  const float* c0    = (const float*)d_in[2];
  const float* W_iou = (const float*)d_in[3];
  const float* U_iou = (const float*)d_in[4];
  const float* b_iou = (const float*)d_in[5];
  const float* U_f_w = (const float*)d_in[6];
  const float* U_f_b = (const float*)d_in[7];
  float* out = (float*)d_out;

  char* ws = (char*)d_ws;
  const size_t wbBytes = (size_t)1280 * 768 * 2;  // 1.97 MB, 16B-aligned
  _Float16* Wb2 = (_Float16*)ws;
  build_wb2<<<3840, 256, 0, stream>>>(Wb2, W_iou, U_iou, U_f_w);

  const size_t cElems = (size_t)NNODES * 256;
  char* p1 = ws + wbBytes;
  if (ws_size >= wbBytes + cElems * 2 + cElems * 2) {
    // c in f16 + h mirrored in f16 (subtree tail requires this layout)
    run_levels<true, _Float16>(x, c0, Wb2, b_iou, U_f_b, out, (_Float16*)p1,
                               (_Float16*)(p1 + cElems * 2), stream);
  } else if (ws_size >= wbBytes + cElems * 4) {
    run_levels<false, float>(x, c0, Wb2, b_iou, U_f_b, out, (float*)p1,
                             nullptr, stream);
  } else {
    run_levels<false, _Float16>(x, c0, Wb2, b_iou, U_f_b, out, (_Float16*)p1,
                                nullptr, stream);
  }
}

// Round 10
// 497.479 us; speedup vs baseline: 1.6909x; 1.6434x over previous
//
#include <hip/hip_runtime.h>
#include <math.h>

#define DEPTH 17
#define NNODES ((1 << DEPTH) - 1)

typedef _Float16 f16x8 __attribute__((ext_vector_type(8)));
typedef float f32x4 __attribute__((ext_vector_type(4)));

// [5/4] Pade tanh, clamped at |x|<=3.4: max err ~1.3e-3 (loose 1.7e-2 tol)
__device__ __forceinline__ float tanhP(float x) {
  float t = fminf(fmaxf(x, -3.4f), 3.4f);
  float s = t * t;
  float num = t * (945.0f + s * (105.0f + s));
  float den = 945.0f + s * (420.0f + 15.0f * s);
  return num * __builtin_amdgcn_rcpf(den);
}
__device__ __forceinline__ float sigP(float x) {
  return 0.5f + 0.5f * tanhP(0.5f * x);
}
__device__ __forceinline__ f16x8 pack8(const float4& a, const float4& b) {
  f16x8 r;
  r[0] = (_Float16)a.x; r[1] = (_Float16)a.y;
  r[2] = (_Float16)a.z; r[3] = (_Float16)a.w;
  r[4] = (_Float16)b.x; r[5] = (_Float16)b.y;
  r[6] = (_Float16)b.z; r[7] = (_Float16)b.w;
  return r;
}

// Lane-order-packed weights: for each (nb, w, g, cb) a 16x32 f16 tile stored
// so lane (q*16+l15) holds elems l15*32 + q*8 .. +7 -> one wave B-fragment =
// contiguous 1 KB, coalesced, L2-resident (1.97 MB total).
__global__ __launch_bounds__(256) void build_wb2(
    _Float16* __restrict__ Wb2, const float* __restrict__ W_iou,
    const float* __restrict__ U_iou, const float* __restrict__ U_f_w) {
  int idx = blockIdx.x * 256 + threadIdx.x;  // grid covers 1280*768 exactly
  int within = idx & 511;                    // l15*32 + kk
  int blk = idx >> 9;                        // ((nb*4+w)*5 + g)*24 + cb
  int l15 = within >> 5;
  int kk = within & 31;
  int cb = blk % 24;
  int t = blk / 24;
  int g = t % 5;
  int t2 = t / 5;
  int w = t2 & 3;
  int nb = t2 >> 2;
  int col = g * 256 + nb * 64 + w * 16 + l15;
  int k = cb * 32 + kk;
  float v;
  if (col < 768)
    v = (k < 256) ? W_iou[col * 256 + k] : U_iou[col * 512 + (k - 256)];
  else
    v = (k < 256) ? 0.0f : U_f_w[(col - 768) * 512 + (k - 256)];
  Wb2[idx] = (_Float16)v;
}

// One level: fused GEMM (A[m,K] @ Wb^T) + TreeLSTM node apply.
// Block tile 64 rows x 64 n (x NG groups); 4 waves; wave w owns all 64 rows
// for n = nb*64 + w*16 + l15 -> wave-local epilogue. A: LDS double-buffered,
// reg-staged dist-2 prefetch; B: register ping-pong from lane-packed Wb2
// (L2-resident, never LDS). Epilogue: padded [64][68] f32 LDS tiles (bank-
// conflict-free scatter-writes AND float4 reads); c-inputs direct-coalesced
// from global; Pade gates (no v_exp).
// NOTE: min-waves MUST stay 2 (R6: min-waves=3 -> 168-reg budget -> scratch
// spill, 1 GB/dispatch). NOTE: per-block n-split (nb) is load-bearing for
// small levels: a block needing all 256 cols must stream all 2 MB of B
// through one CU (R9 tail: 312 us for 63 nodes).
template <bool LEAF, bool H16, typename CT>
__device__ __forceinline__ void level_body(
    const float* __restrict__ x, const float* __restrict__ c0in,
    const _Float16* __restrict__ Wb2, const float* __restrict__ b_iou,
    const float* __restrict__ U_f_b, float* __restrict__ out,
    CT* __restrict__ cws, _Float16* __restrict__ hws, int m, int off,
    int coff, int r, int nb) {
  constexpr int NG = LEAF ? 3 : 5;    // gate groups of 64 output cols
  constexpr int NCH = LEAF ? 4 : 12;  // K / 64 (even)
  constexpr int NBU = NG * 2;         // B f16x8 fragments per chunk
  __shared__ __align__(16) char smem[34816];  // max(16K main, 2x[64][68]f32)
  f16x8* sA = (f16x8*)smem;

  const int tid = threadIdx.x;
  const int w = tid >> 6;
  const int lane = tid & 63;
  const int l15 = lane & 15;
  const int q = lane >> 4;
  const int pbase = r << 6;
  const int arow = tid >> 3;
  const int akc = tid & 7;

  auto LOADA = [&](float4 (&ax)[2][2], f16x8 (&ah)[2], int c) {
    const int k0 = (c << 6) + (akc << 3);
#pragma unroll
    for (int j = 0; j < 2; ++j) {
      const int row = arow + j * 32;
      const int p = pbase + row;
      const bool xpart = LEAF || c < 4;
      if (p < m) {
        if (xpart) {
          const float* src = x + (size_t)(off + p) * 256 + k0;
          ax[j][0] = *(const float4*)src;
          ax[j][1] = *(const float4*)(src + 4);
        } else if (H16) {
          ah[j] = *(const f16x8*)(hws + (size_t)(coff + 2 * p) * 256 +
                                  (k0 - 256));
        } else {
          const float* src = out + (size_t)(coff + 2 * p) * 256 + (k0 - 256);
          ax[j][0] = *(const float4*)src;
          ax[j][1] = *(const float4*)(src + 4);
        }
      } else {
        ax[j][0] = float4{0.f, 0.f, 0.f, 0.f};
        ax[j][1] = float4{0.f, 0.f, 0.f, 0.f};
        f16x8 z = {};
        ah[j] = z;
      }
    }
  };

  auto WRITEA = [&](float4 (&ax)[2][2], f16x8 (&ah)[2], int c) {
#pragma unroll
    for (int j = 0; j < 2; ++j) {
      const int row = arow + j * 32;
      f16x8 v;
      if (H16 && !LEAF && c >= 4) {
        v = ah[j];
      } else {
        v = pack8(ax[j][0], ax[j][1]);
      }
      sA[((c & 1) << 9) | (row << 3) | (akc ^ (row & 7))] = v;
    }
  };

  const _Float16* bb =
      Wb2 + (size_t)(nb * 4 + w) * (5 * 24 * 512) + l15 * 32 + q * 8;
  auto LOADB = [&](f16x8 (&bv)[NBU], int c) {
#pragma unroll
    for (int j = 0; j < NBU; ++j)
      bv[j] = *(const f16x8*)(bb + (((j >> 1) * 24 + c * 2 + (j & 1)) << 9));
  };

  f32x4 acc[NG][4] = {};

  auto COMPUTE = [&](int buf, f16x8 (&bv)[NBU]) {
    __builtin_amdgcn_s_setprio(1);
#pragma unroll
    for (int ks = 0; ks < 2; ++ks) {
      f16x8 af[4];
#pragma unroll
      for (int rf = 0; rf < 4; ++rf) {
        const int row = rf * 16 + l15;
        af[rf] = sA[(buf << 9) | (row << 3) | ((ks * 4 + q) ^ (row & 7))];
      }
#pragma unroll
      for (int g = 0; g < NG; ++g) {
        const f16x8 bf = bv[g * 2 + ks];
#pragma unroll
        for (int rf = 0; rf < 4; ++rf)
          acc[g][rf] = __builtin_amdgcn_mfma_f32_16x16x32_f16(
              af[rf], bf, acc[g][rf], 0, 0, 0);
      }
    }
    __builtin_amdgcn_s_setprio(0);
  };

  float4 axA[2][2], axB[2][2];
  f16x8 ahA[2], ahB[2];
  f16x8 bvA[NBU], bvB[NBU];

  LOADA(axA, ahA, 0);
  LOADB(bvA, 0);
  WRITEA(axA, ahA, 0);
  LOADA(axB, ahB, 1);
  LOADB(bvB, 1);
  __syncthreads();

  for (int c = 0; c < NCH; c += 2) {
    if (c + 2 < NCH) LOADA(axA, ahA, c + 2);
    COMPUTE(0, bvA);
    WRITEA(axB, ahB, c + 1);
    if (c + 2 < NCH) LOADB(bvA, c + 2);
    __syncthreads();
    if (c + 3 < NCH) LOADA(axB, ahB, c + 3);
    COMPUTE(1, bvB);
    if (c + 2 < NCH) {
      WRITEA(axA, ahA, c + 2);
      if (c + 3 < NCH) LOADB(bvB, c + 3);
      __syncthreads();
    }
  }
  __syncthreads();  // main loop done; smem free for epilogue

  // ===== epilogue: padded-tile transpose, all global I/O coalesced ========
  const int erow = tid >> 2;
  const int eseg = tid & 3;
  const int p_e = pbase + erow;
  const bool pv = p_e < m;
  float* T0 = (float*)smem;            // [64][68] f32
  float* T1 = T0 + 64 * 68;
  const int scol = (w << 4) + l15;
  const int n = (nb << 6) + scol;
  const int rbase = erow * 68 + (eseg << 4);

  float cred[16];
  if constexpr (!LEAF) {
    float c0v[16], c1v[16];
    if (pv) {
      const CT* csrc =
          cws + (size_t)(coff + 2 * p_e) * 256 + (nb << 6) + (eseg << 4);
      if constexpr (sizeof(CT) == 2) {
        f16x8 a0 = *(const f16x8*)csrc;
        f16x8 a1 = *(const f16x8*)(csrc + 8);
        f16x8 b0 = *(const f16x8*)(csrc + 256);
        f16x8 b1 = *(const f16x8*)(csrc + 264);
#pragma unroll
        for (int j = 0; j < 8; ++j) {
          c0v[j] = (float)a0[j]; c0v[8 + j] = (float)a1[j];
          c1v[j] = (float)b0[j]; c1v[8 + j] = (float)b1[j];
        }
      } else {
#pragma unroll
        for (int jj = 0; jj < 4; ++jj) {
          float4 v0 = *(const float4*)((const float*)csrc + jj * 4);
          float4 v1 = *(const float4*)((const float*)csrc + 256 + jj * 4);
          c0v[jj * 4 + 0] = v0.x; c0v[jj * 4 + 1] = v0.y;
          c0v[jj * 4 + 2] = v0.z; c0v[jj * 4 + 3] = v0.w;
          c1v[jj * 4 + 0] = v1.x; c1v[jj * 4 + 1] = v1.y;
          c1v[jj * 4 + 2] = v1.z; c1v[jj * 4 + 3] = v1.w;
        }
      }
    } else {
#pragma unroll
      for (int j = 0; j < 16; ++j) { c0v[j] = 0.f; c1v[j] = 0.f; }
    }
    const float bf0 = U_f_b[n], bf1 = U_f_b[256 + n];
#pragma unroll
    for (int rf = 0; rf < 4; ++rf)
#pragma unroll
      for (int rr = 0; rr < 4; ++rr) {
        const int prow = rf * 16 + (q << 2) + rr;
        T0[prow * 68 + scol] = sigP(acc[3][rf][rr] + bf0);
        T1[prow * 68 + scol] = sigP(acc[4][rf][rr] + bf1);
      }
    __syncthreads();
#pragma unroll
    for (int jj = 0; jj < 4; ++jj) {
      float4 f04 = *(const float4*)&T0[rbase + jj * 4];
      float4 f14 = *(const float4*)&T1[rbase + jj * 4];
      cred[jj * 4 + 0] = f04.x * c0v[jj * 4 + 0] + f14.x * c1v[jj * 4 + 0];
      cred[jj * 4 + 1] = f04.y * c0v[jj * 4 + 1] + f14.y * c1v[jj * 4 + 1];
      cred[jj * 4 + 2] = f04.z * c0v[jj * 4 + 2] + f14.z * c1v[jj * 4 + 2];
      cred[jj * 4 + 3] = f04.w * c0v[jj * 4 + 3] + f14.w * c1v[jj * 4 + 3];
    }
    __syncthreads();
  } else {
    if (pv) {
      const float* src =
          c0in + (size_t)(off + p_e) * 256 + (nb << 6) + (eseg << 4);
#pragma unroll
      for (int jj = 0; jj < 4; ++jj) {
        float4 v = *(const float4*)(src + jj * 4);
        cred[jj * 4 + 0] = v.x; cred[jj * 4 + 1] = v.y;
        cred[jj * 4 + 2] = v.z; cred[jj * 4 + 3] = v.w;
      }
    } else {
#pragma unroll
      for (int j = 0; j < 16; ++j) cred[j] = 0.f;
    }
  }

  {
    const float bi = b_iou[n], bo = b_iou[256 + n], bu = b_iou[512 + n];
#pragma unroll
    for (int rf = 0; rf < 4; ++rf)
#pragma unroll
      for (int rr = 0; rr < 4; ++rr) {
        const int prow = rf * 16 + (q << 2) + rr;
        const float iv = sigP(acc[0][rf][rr] + bi);
        const float uv = tanhP(acc[2][rf][rr] + bu);
        const float ov = sigP(acc[1][rf][rr] + bo);
        T0[prow * 68 + scol] = iv * uv;
        T1[prow * 68 + scol] = ov;
      }
  }
  __syncthreads();

  if (pv) {
    float4 h4[4], c4[4];
#pragma unroll
    for (int jj = 0; jj < 4; ++jj) {
      float4 iu4 = *(const float4*)&T0[rbase + jj * 4];
      float4 o4 = *(const float4*)&T1[rbase + jj * 4];
      float cc;
      cc = iu4.x + cred[jj * 4 + 0]; c4[jj].x = cc; h4[jj].x = o4.x * tanhP(cc);
      cc = iu4.y + cred[jj * 4 + 1]; c4[jj].y = cc; h4[jj].y = o4.y * tanhP(cc);
      cc = iu4.z + cred[jj * 4 + 2]; c4[jj].z = cc; h4[jj].z = o4.z * tanhP(cc);
      cc = iu4.w + cred[jj * 4 + 3]; c4[jj].w = cc; h4[jj].w = o4.w * tanhP(cc);
    }
    const size_t ob = (size_t)(off + p_e) * 256 + (nb << 6) + (eseg << 4);
    float* dst = out + ob;
#pragma unroll
    for (int jj = 0; jj < 4; ++jj) *(float4*)(dst + jj * 4) = h4[jj];
    if constexpr (H16) {
      *(f16x8*)(hws + ob) = pack8(h4[0], h4[1]);
      *(f16x8*)(hws + ob + 8) = pack8(h4[2], h4[3]);
    }
    if constexpr (sizeof(CT) == 2) {
      *(f16x8*)((_Float16*)cws + ob) = pack8(c4[0], c4[1]);
      *(f16x8*)((_Float16*)cws + ob + 8) = pack8(c4[2], c4[3]);
    } else {
      float* cdst = (float*)cws + ob;
#pragma unroll
      for (int jj = 0; jj < 4; ++jj) *(float4*)(cdst + jj * 4) = c4[jj];
    }
  }
}

template <bool LEAF, bool H16, typename CT>
__global__ __launch_bounds__(256, 2) void level_kernel(
    const float* __restrict__ x, const float* __restrict__ c0in,
    const _Float16* __restrict__ Wb2, const float* __restrict__ b_iou,
    const float* __restrict__ U_f_b, float* __restrict__ out,
    CT* __restrict__ cws, _Float16* __restrict__ hws, int m, int off,
    int coff) {
  int bx = blockIdx.x, r, nb;
  if ((gridDim.x & 31) == 0) {  // XCD-grouped: nb-splits share bid%8
    nb = (bx >> 3) & 3;
    r = ((bx >> 5) << 3) + (bx & 7);
  } else {
    r = bx >> 2;
    nb = bx & 3;
  }
  level_body<LEAF, H16, CT>(x, c0in, Wb2, b_iou, U_f_b, out, cws, hws, m, off,
                            coff, r, nb);
}

// ============================== dispatch ===================================
template <bool H16, typename CT>
static void run_levels(const float* x, const float* c0, const _Float16* Wb2,
                       const float* b_iou, const float* U_f_b, float* out,
                       CT* cws, _Float16* hws, hipStream_t stream) {
  level_kernel<true, H16, CT><<<dim3(4096), 256, 0, stream>>>(
      x, c0, Wb2, b_iou, U_f_b, out, cws, hws, 65536, 65535, 0);
  for (int k = DEPTH - 2; k >= 0; --k) {
    const int m = 1 << k;
    const int R = (m + 63) / 64;
    level_kernel<false, H16, CT><<<dim3(R * 4), 256, 0, stream>>>(
        x, c0, Wb2, b_iou, U_f_b, out, cws, hws, m, m - 1, 2 * m - 1);
  }
}

extern "C" void kernel_launch(void* const* d_in, const int* in_sizes, int n_in,
                              void* d_out, int out_size, void* d_ws, size_t ws_size,
                              hipStream_t stream) {
  const float* x     = (const float*)d_in[0];
  // d_in[1] = h0 (unused by the reference's math)
  const float* c0    = (const float*)d_in[2];
  const float* W_iou = (const float*)d_in[3];
  const float* U_iou = (const float*)d_in[4];
  const float* b_iou = (const float*)d_in[5];
  const float* U_f_w = (const float*)d_in[6];
  const float* U_f_b = (const float*)d_in[7];
  float* out = (float*)d_out;

  char* ws = (char*)d_ws;
  const size_t wbBytes = (size_t)1280 * 768 * 2;  // 1.97 MB, 16B-aligned
  _Float16* Wb2 = (_Float16*)ws;
  build_wb2<<<3840, 256, 0, stream>>>(Wb2, W_iou, U_iou, U_f_w);

  const size_t cElems = (size_t)NNODES * 256;
  char* p1 = ws + wbBytes;
  if (ws_size >= wbBytes + cElems * 2 + cElems * 2) {
    // c in f16 (halved traffic) + h mirrored in f16 for the parent GEMM
    run_levels<true, _Float16>(x, c0, Wb2, b_iou, U_f_b, out, (_Float16*)p1,
                               (_Float16*)(p1 + cElems * 2), stream);
  } else if (ws_size >= wbBytes + cElems * 4) {
    run_levels<false, float>(x, c0, Wb2, b_iou, U_f_b, out, (float*)p1,
                             nullptr, stream);
  } else {
    run_levels<false, _Float16>(x, c0, Wb2, b_iou, U_f_b, out, (_Float16*)p1,
                                nullptr, stream);
  }
}

// Round 12
// 488.648 us; speedup vs baseline: 1.7214x; 1.0181x over previous
//
#include <hip/hip_runtime.h>
#include <math.h>

#define DEPTH 17
#define NNODES ((1 << DEPTH) - 1)

typedef _Float16 f16x8 __attribute__((ext_vector_type(8)));
typedef float f32x4 __attribute__((ext_vector_type(4)));

// [5/4] Pade tanh, clamped at |x|<=3.4: max err ~1.3e-3 (loose 1.7e-2 tol)
__device__ __forceinline__ float tanhP(float x) {
  float t = fminf(fmaxf(x, -3.4f), 3.4f);
  float s = t * t;
  float num = t * (945.0f + s * (105.0f + s));
  float den = 945.0f + s * (420.0f + 15.0f * s);
  return num * __builtin_amdgcn_rcpf(den);
}
__device__ __forceinline__ float sigP(float x) {
  return 0.5f + 0.5f * tanhP(0.5f * x);
}
__device__ __forceinline__ f16x8 pack8(const float4& a, const float4& b) {
  f16x8 r;
  r[0] = (_Float16)a.x; r[1] = (_Float16)a.y;
  r[2] = (_Float16)a.z; r[3] = (_Float16)a.w;
  r[4] = (_Float16)b.x; r[5] = (_Float16)b.y;
  r[6] = (_Float16)b.z; r[7] = (_Float16)b.w;
  return r;
}

// Lane-order-packed weights: for each (nb, w, g, cb) a 16x32 f16 tile stored
// so lane (q*16+l15) holds elems l15*32 + q*8 .. +7 -> one wave B-fragment =
// contiguous 1 KB, coalesced, L2-resident (1.97 MB total).
__global__ __launch_bounds__(256) void build_wb2(
    _Float16* __restrict__ Wb2, const float* __restrict__ W_iou,
    const float* __restrict__ U_iou, const float* __restrict__ U_f_w) {
  int idx = blockIdx.x * 256 + threadIdx.x;  // grid covers 1280*768 exactly
  int within = idx & 511;                    // l15*32 + kk
  int blk = idx >> 9;                        // ((nb*4+w)*5 + g)*24 + cb
  int l15 = within >> 5;
  int kk = within & 31;
  int cb = blk % 24;
  int t = blk / 24;
  int g = t % 5;
  int t2 = t / 5;
  int w = t2 & 3;
  int nb = t2 >> 2;
  int col = g * 256 + nb * 64 + w * 16 + l15;
  int k = cb * 32 + kk;
  float v;
  if (col < 768)
    v = (k < 256) ? W_iou[col * 256 + k] : U_iou[col * 512 + (k - 256)];
  else
    v = (k < 256) ? 0.0f : U_f_w[(col - 768) * 512 + (k - 256)];
  Wb2[idx] = (_Float16)v;
}

// One level: fused GEMM (A[m,K] @ Wb^T) + TreeLSTM node apply.
// Block tile 64 rows x 64 n (x NG groups); 4 waves; wave w owns all 64 rows
// for n = nb*64 + w*16 + l15 -> wave-local epilogue.
// Internal H16+f16 path (NEWP): chunks 0-3 (x, f32->f16) reg-staged; chunks
// 4-11 (h16) async-staged via global_load_lds with linear LDS dest +
// inverse-swizzled per-lane source (rule 21). f-gate groups (g=3,4) skipped
// for chunks<4 (their Wb2 block is zero): -13% MFMA and B traffic.
// Pipeline invariant: at iteration c, fill chunk c+1 into buf (c+1)&1 (that
// buffer was retired by COMP(c-1) at the last barrier). Chunks 0 AND 1 are
// pre-staged by the prologue, so fills begin at chunk 2 (R11 bug: filling
// chunk "1" at c=0 clobbered buf1 with axB's chunk-3 data).
// B: register ping-pong from lane-packed Wb2 (L2-resident). Epilogue: padded
// [64][68] f32 LDS tiles; c-inputs direct-coalesced; Pade gates.
// NOTE: min-waves stays 2 (R6: forcing 3 spilled -> 1 GB/dispatch scratch).
// NOTE: per-block n-split (nb) is load-bearing (R9: full-width block = 2 MB
// of B through one CU). No s_setprio (m190: hurts lockstep GEMM).
template <bool LEAF, bool H16, typename CT>
__device__ __forceinline__ void level_body(
    const float* __restrict__ x, const float* __restrict__ c0in,
    const _Float16* __restrict__ Wb2, const float* __restrict__ b_iou,
    const float* __restrict__ U_f_b, float* __restrict__ out,
    CT* __restrict__ cws, _Float16* __restrict__ hws, int m, int off,
    int coff, int r, int nb) {
  constexpr int NG = LEAF ? 3 : 5;    // gate groups of 64 output cols
  constexpr int NCH = LEAF ? 4 : 12;  // K / 64 (even)
  constexpr int NBU = NG * 2;         // B f16x8 fragments per chunk
  constexpr bool NEWP = (!LEAF) && H16 && (sizeof(CT) == 2);
  __shared__ __align__(16) char smem[34816];  // max(16K main, 2x[64][68]f32)
  f16x8* sA = (f16x8*)smem;

  const int tid = threadIdx.x;
  const int w = tid >> 6;
  const int lane = tid & 63;
  const int l15 = lane & 15;
  const int q = lane >> 4;
  const int pbase = r << 6;
  const int arow = tid >> 3;
  const int akc = tid & 7;

  const _Float16* bb =
      Wb2 + (size_t)(nb * 4 + w) * (5 * 24 * 512) + l15 * 32 + q * 8;

  f32x4 acc[NG][4] = {};

  if constexpr (NEWP) {
    // ---- internal pipeline: x reg-staged, h16 via global_load_lds --------
    const int ku = akc ^ (arow & 7);  // same for both row j's (rows differ by 32)
    int prowA = pbase + arow;
    if (prowA >= m) prowA = pbase;
    int prowB = pbase + arow + 32;
    if (prowB >= m) prowB = pbase;

    auto LOADAx = [&](float4 (&ax)[2][2], int c) {  // x f32, logical akc unit
      const int k0 = (c << 6) + (akc << 3);
#pragma unroll
      for (int j = 0; j < 2; ++j) {
        const int prow = j ? prowB : prowA;
        const float* src = x + (size_t)(off + prow) * 256 + k0;
        ax[j][0] = *(const float4*)src;
        ax[j][1] = *(const float4*)(src + 4);
      }
    };
    auto WRITEAx = [&](float4 (&ax)[2][2], int c) {
#pragma unroll
      for (int j = 0; j < 2; ++j) {
        const int row = arow + j * 32;
        sA[((c & 1) << 9) | (row << 3) | (akc ^ (row & 7))] =
            pack8(ax[j][0], ax[j][1]);
      }
    };
    auto STAGE = [&](int c, int buf) {  // h16 via gload_lds, linear dest
#pragma unroll
      for (int j = 0; j < 2; ++j) {
        const int prow = j ? prowB : prowA;
        const int kk = ((c - 4) << 6) + (ku << 3);  // 0..504
        const _Float16* src =
            hws + ((size_t)(coff + 2 * prow + (kk >> 8)) << 8) + (kk & 255);
        __builtin_amdgcn_global_load_lds(
            (const __attribute__((address_space(1))) void*)src,
            (__attribute__((address_space(3))) void*)(sA + (buf << 9) +
                                                      (j << 8) + tid),
            16, 0, 0);
      }
    };
    auto LOADBn = [&](f16x8 (&bv)[10], int c, int nbu) {
#pragma unroll
      for (int j = 0; j < 10; ++j)
        if (j < nbu)
          bv[j] =
              *(const f16x8*)(bb + (((j >> 1) * 24 + c * 2 + (j & 1)) << 9));
    };
    auto COMP = [&](int buf, f16x8 (&bv)[10], int ng) {
#pragma unroll
      for (int ks = 0; ks < 2; ++ks) {
        f16x8 af[4];
#pragma unroll
        for (int rf = 0; rf < 4; ++rf) {
          const int rowr = rf * 16 + l15;
          af[rf] = sA[(buf << 9) | (rowr << 3) | ((ks * 4 + q) ^ (rowr & 7))];
        }
#pragma unroll
        for (int g = 0; g < 5; ++g)
          if (g < ng) {
            const f16x8 bf = bv[g * 2 + ks];
#pragma unroll
            for (int rf = 0; rf < 4; ++rf)
              acc[g][rf] = __builtin_amdgcn_mfma_f32_16x16x32_f16(
                  af[rf], bf, acc[g][rf], 0, 0, 0);
          }
      }
    };

    float4 axA[2][2], axB[2][2];
    f16x8 bvA[10], bvB[10];
    LOADAx(axA, 0);
    LOADAx(axB, 1);
    LOADBn(bvA, 0, 6);
    LOADBn(bvB, 1, 6);
    WRITEAx(axA, 0);   // chunk 0 -> buf 0
    LOADAx(axA, 2);    // axA <- chunk 2
    WRITEAx(axB, 1);   // chunk 1 -> buf 1
    LOADAx(axB, 3);    // axB <- chunk 3
    __syncthreads();

#pragma unroll
    for (int c = 0; c < 12; ++c) {
      // fill chunk c+1 into buf (c+1)&1 (retired at the previous barrier);
      // chunks 0,1 were pre-staged by the prologue -> fills start at 2.
      if (c + 1 >= 2 && c + 1 < 12) {
        if (c + 1 < 4) {
          if ((c + 1) & 1) WRITEAx(axB, c + 1);
          else WRITEAx(axA, c + 1);
        } else {
          STAGE(c + 1, (c + 1) & 1);
        }
      }
      if (c & 1) COMP(1, bvB, c < 4 ? 3 : 5);
      else COMP(0, bvA, c < 4 ? 3 : 5);
      if (c + 2 < 12) {
        if (c & 1) LOADBn(bvB, c + 2, (c + 2) < 4 ? 6 : 10);
        else LOADBn(bvA, c + 2, (c + 2) < 4 ? 6 : 10);
      }
      __syncthreads();  // retires this chunk's reads; drains STAGE(c+1)
    }
    __syncthreads();
  } else {
    // ---- R10 reg-staged pipeline (leaf + fallbacks) ----------------------
    auto LOADA = [&](float4 (&ax)[2][2], f16x8 (&ah)[2], int c) {
      const int k0 = (c << 6) + (akc << 3);
#pragma unroll
      for (int j = 0; j < 2; ++j) {
        const int row = arow + j * 32;
        const int p = pbase + row;
        const bool xpart = LEAF || c < 4;
        if (p < m) {
          if (xpart) {
            const float* src = x + (size_t)(off + p) * 256 + k0;
            ax[j][0] = *(const float4*)src;
            ax[j][1] = *(const float4*)(src + 4);
          } else if (H16) {
            ah[j] = *(const f16x8*)(hws + (size_t)(coff + 2 * p) * 256 +
                                    (k0 - 256));
          } else {
            const float* src = out + (size_t)(coff + 2 * p) * 256 + (k0 - 256);
            ax[j][0] = *(const float4*)src;
            ax[j][1] = *(const float4*)(src + 4);
          }
        } else {
          ax[j][0] = float4{0.f, 0.f, 0.f, 0.f};
          ax[j][1] = float4{0.f, 0.f, 0.f, 0.f};
          f16x8 z = {};
          ah[j] = z;
        }
      }
    };
    auto WRITEA = [&](float4 (&ax)[2][2], f16x8 (&ah)[2], int c) {
#pragma unroll
      for (int j = 0; j < 2; ++j) {
        const int row = arow + j * 32;
        f16x8 v;
        if (H16 && !LEAF && c >= 4) v = ah[j];
        else v = pack8(ax[j][0], ax[j][1]);
        sA[((c & 1) << 9) | (row << 3) | (akc ^ (row & 7))] = v;
      }
    };
    auto LOADB = [&](f16x8 (&bv)[NBU], int c) {
#pragma unroll
      for (int j = 0; j < NBU; ++j)
        bv[j] =
            *(const f16x8*)(bb + (((j >> 1) * 24 + c * 2 + (j & 1)) << 9));
    };
    auto COMPUTE = [&](int buf, f16x8 (&bv)[NBU]) {
#pragma unroll
      for (int ks = 0; ks < 2; ++ks) {
        f16x8 af[4];
#pragma unroll
        for (int rf = 0; rf < 4; ++rf) {
          const int row = rf * 16 + l15;
          af[rf] = sA[(buf << 9) | (row << 3) | ((ks * 4 + q) ^ (row & 7))];
        }
#pragma unroll
        for (int g = 0; g < NG; ++g) {
          const f16x8 bf = bv[g * 2 + ks];
#pragma unroll
          for (int rf = 0; rf < 4; ++rf)
            acc[g][rf] = __builtin_amdgcn_mfma_f32_16x16x32_f16(
                af[rf], bf, acc[g][rf], 0, 0, 0);
        }
      }
    };

    float4 axA[2][2], axB[2][2];
    f16x8 ahA[2], ahB[2];
    f16x8 bvA[NBU], bvB[NBU];

    LOADA(axA, ahA, 0);
    LOADB(bvA, 0);
    WRITEA(axA, ahA, 0);
    LOADA(axB, ahB, 1);
    LOADB(bvB, 1);
    __syncthreads();

    for (int c = 0; c < NCH; c += 2) {
      if (c + 2 < NCH) LOADA(axA, ahA, c + 2);
      COMPUTE(0, bvA);
      WRITEA(axB, ahB, c + 1);
      if (c + 2 < NCH) LOADB(bvA, c + 2);
      __syncthreads();
      if (c + 3 < NCH) LOADA(axB, ahB, c + 3);
      COMPUTE(1, bvB);
      if (c + 2 < NCH) {
        WRITEA(axA, ahA, c + 2);
        if (c + 3 < NCH) LOADB(bvB, c + 3);
        __syncthreads();
      }
    }
    __syncthreads();
  }

  // ===== epilogue: padded-tile transpose, all global I/O coalesced ========
  const int erow = tid >> 2;
  const int eseg = tid & 3;
  const int p_e = pbase + erow;
  const bool pv = p_e < m;
  float* T0 = (float*)smem;            // [64][68] f32
  float* T1 = T0 + 64 * 68;
  const int scol = (w << 4) + l15;
  const int n = (nb << 6) + scol;
  const int rbase = erow * 68 + (eseg << 4);

  float cred[16];
  if constexpr (!LEAF) {
    float c0v[16], c1v[16];
    if (pv) {
      const CT* csrc =
          cws + (size_t)(coff + 2 * p_e) * 256 + (nb << 6) + (eseg << 4);
      if constexpr (sizeof(CT) == 2) {
        f16x8 a0 = *(const f16x8*)csrc;
        f16x8 a1 = *(const f16x8*)(csrc + 8);
        f16x8 b0 = *(const f16x8*)(csrc + 256);
        f16x8 b1 = *(const f16x8*)(csrc + 264);
#pragma unroll
        for (int j = 0; j < 8; ++j) {
          c0v[j] = (float)a0[j]; c0v[8 + j] = (float)a1[j];
          c1v[j] = (float)b0[j]; c1v[8 + j] = (float)b1[j];
        }
      } else {
#pragma unroll
        for (int jj = 0; jj < 4; ++jj) {
          float4 v0 = *(const float4*)((const float*)csrc + jj * 4);
          float4 v1 = *(const float4*)((const float*)csrc + 256 + jj * 4);
          c0v[jj * 4 + 0] = v0.x; c0v[jj * 4 + 1] = v0.y;
          c0v[jj * 4 + 2] = v0.z; c0v[jj * 4 + 3] = v0.w;
          c1v[jj * 4 + 0] = v1.x; c1v[jj * 4 + 1] = v1.y;
          c1v[jj * 4 + 2] = v1.z; c1v[jj * 4 + 3] = v1.w;
        }
      }
    } else {
#pragma unroll
      for (int j = 0; j < 16; ++j) { c0v[j] = 0.f; c1v[j] = 0.f; }
    }
    const float bf0 = U_f_b[n], bf1 = U_f_b[256 + n];
#pragma unroll
    for (int rf = 0; rf < 4; ++rf)
#pragma unroll
      for (int rr = 0; rr < 4; ++rr) {
        const int prow = rf * 16 + (q << 2) + rr;
        T0[prow * 68 + scol] = sigP(acc[3][rf][rr] + bf0);
        T1[prow * 68 + scol] = sigP(acc[4][rf][rr] + bf1);
      }
    __syncthreads();
#pragma unroll
    for (int jj = 0; jj < 4; ++jj) {
      float4 f04 = *(const float4*)&T0[rbase + jj * 4];
      float4 f14 = *(const float4*)&T1[rbase + jj * 4];
      cred[jj * 4 + 0] = f04.x * c0v[jj * 4 + 0] + f14.x * c1v[jj * 4 + 0];
      cred[jj * 4 + 1] = f04.y * c0v[jj * 4 + 1] + f14.y * c1v[jj * 4 + 1];
      cred[jj * 4 + 2] = f04.z * c0v[jj * 4 + 2] + f14.z * c1v[jj * 4 + 2];
      cred[jj * 4 + 3] = f04.w * c0v[jj * 4 + 3] + f14.w * c1v[jj * 4 + 3];
    }
    __syncthreads();
  } else {
    if (pv) {
      const float* src =
          c0in + (size_t)(off + p_e) * 256 + (nb << 6) + (eseg << 4);
#pragma unroll
      for (int jj = 0; jj < 4; ++jj) {
        float4 v = *(const float4*)(src + jj * 4);
        cred[jj * 4 + 0] = v.x; cred[jj * 4 + 1] = v.y;
        cred[jj * 4 + 2] = v.z; cred[jj * 4 + 3] = v.w;
      }
    } else {
#pragma unroll
      for (int j = 0; j < 16; ++j) cred[j] = 0.f;
    }
  }

  {
    const float bi = b_iou[n], bo = b_iou[256 + n], bu = b_iou[512 + n];
#pragma unroll
    for (int rf = 0; rf < 4; ++rf)
#pragma unroll
      for (int rr = 0; rr < 4; ++rr) {
        const int prow = rf * 16 + (q << 2) + rr;
        const float iv = sigP(acc[0][rf][rr] + bi);
        const float uv = tanhP(acc[2][rf][rr] + bu);
        const float ov = sigP(acc[1][rf][rr] + bo);
        T0[prow * 68 + scol] = iv * uv;
        T1[prow * 68 + scol] = ov;
      }
  }
  __syncthreads();

  if (pv) {
    float4 h4[4], c4[4];
#pragma unroll
    for (int jj = 0; jj < 4; ++jj) {
      float4 iu4 = *(const float4*)&T0[rbase + jj * 4];
      float4 o4 = *(const float4*)&T1[rbase + jj * 4];
      float cc;
      cc = iu4.x + cred[jj * 4 + 0]; c4[jj].x = cc; h4[jj].x = o4.x * tanhP(cc);
      cc = iu4.y + cred[jj * 4 + 1]; c4[jj].y = cc; h4[jj].y = o4.y * tanhP(cc);
      cc = iu4.z + cred[jj * 4 + 2]; c4[jj].z = cc; h4[jj].z = o4.z * tanhP(cc);
      cc = iu4.w + cred[jj * 4 + 3]; c4[jj].w = cc; h4[jj].w = o4.w * tanhP(cc);
    }
    const size_t ob = (size_t)(off + p_e) * 256 + (nb << 6) + (eseg << 4);
    float* dst = out + ob;
#pragma unroll
    for (int jj = 0; jj < 4; ++jj) *(float4*)(dst + jj * 4) = h4[jj];
    if constexpr (H16) {
      *(f16x8*)(hws + ob) = pack8(h4[0], h4[1]);
      *(f16x8*)(hws + ob + 8) = pack8(h4[2], h4[3]);
    }
    if constexpr (sizeof(CT) == 2) {
      *(f16x8*)((_Float16*)cws + ob) = pack8(c4[0], c4[1]);
      *(f16x8*)((_Float16*)cws + ob + 8) = pack8(c4[2], c4[3]);
    } else {
      float* cdst = (float*)cws + ob;
#pragma unroll
      for (int jj = 0; jj < 4; ++jj) *(float4*)(cdst + jj * 4) = c4[jj];
    }
  }
}

template <bool LEAF, bool H16, typename CT>
__global__ __launch_bounds__(256, 2) void level_kernel(
    const float* __restrict__ x, const float* __restrict__ c0in,
    const _Float16* __restrict__ Wb2, const float* __restrict__ b_iou,
    const float* __restrict__ U_f_b, float* __restrict__ out,
    CT* __restrict__ cws, _Float16* __restrict__ hws, int m, int off,
    int coff) {
  int bx = blockIdx.x, r, nb;
  if ((gridDim.x & 31) == 0) {  // XCD-grouped: nb-splits share bid%8
    nb = (bx >> 3) & 3;
    r = ((bx >> 5) << 3) + (bx & 7);
  } else {
    r = bx >> 2;
    nb = bx & 3;
  }
  level_body<LEAF, H16, CT>(x, c0in, Wb2, b_iou, U_f_b, out, cws, hws, m, off,
                            coff, r, nb);
}

// ============================== dispatch ===================================
template <bool H16, typename CT>
static void run_levels(const float* x, const float* c0, const _Float16* Wb2,
                       const float* b_iou, const float* U_f_b, float* out,
                       CT* cws, _Float16* hws, hipStream_t stream) {
  level_kernel<true, H16, CT><<<dim3(4096), 256, 0, stream>>>(
      x, c0, Wb2, b_iou, U_f_b, out, cws, hws, 65536, 65535, 0);
  for (int k = DEPTH - 2; k >= 0; --k) {
    const int m = 1 << k;
    const int R = (m + 63) / 64;
    level_kernel<false, H16, CT><<<dim3(R * 4), 256, 0, stream>>>(
        x, c0, Wb2, b_iou, U_f_b, out, cws, hws, m, m - 1, 2 * m - 1);
  }
}

extern "C" void kernel_launch(void* const* d_in, const int* in_sizes, int n_in,
                              void* d_out, int out_size, void* d_ws, size_t ws_size,
                              hipStream_t stream) {
  const float* x     = (const float*)d_in[0];
  // d_in[1] = h0 (unused by the reference's math)
  const float* c0    = (const float*)d_in[2];
  const float* W_iou = (const float*)d_in[3];
  const float* U_iou = (const float*)d_in[4];
  const float* b_iou = (const float*)d_in[5];
  const float* U_f_w = (const float*)d_in[6];
  const float* U_f_b = (const float*)d_in[7];
  float* out = (float*)d_out;

  char* ws = (char*)d_ws;
  const size_t wbBytes = (size_t)1280 * 768 * 2;  // 1.97 MB, 16B-aligned
  _Float16* Wb2 = (_Float16*)ws;
  build_wb2<<<3840, 256, 0, stream>>>(Wb2, W_iou, U_iou, U_f_w);

  const size_t cElems = (size_t)NNODES * 256;
  char* p1 = ws + wbBytes;
  if (ws_size >= wbBytes + cElems * 2 + cElems * 2) {
    // c in f16 (halved traffic) + h mirrored in f16 for the parent GEMM
    run_levels<true, _Float16>(x, c0, Wb2, b_iou, U_f_b, out, (_Float16*)p1,
                               (_Float16*)(p1 + cElems * 2), stream);
  } else if (ws_size >= wbBytes + cElems * 4) {
    run_levels<false, float>(x, c0, Wb2, b_iou, U_f_b, out, (float*)p1,
                             nullptr, stream);
  } else {
    run_levels<false, _Float16>(x, c0, Wb2, b_iou, U_f_b, out, (_Float16*)p1,
                                nullptr, stream);
  }
}

// Round 13
// 479.502 us; speedup vs baseline: 1.7543x; 1.0191x over previous
//
#include <hip/hip_runtime.h>
#include <math.h>

#define DEPTH 17
#define NNODES ((1 << DEPTH) - 1)

typedef _Float16 f16x8 __attribute__((ext_vector_type(8)));
typedef float f32x4 __attribute__((ext_vector_type(4)));

// [5/4] Pade tanh, clamped at |x|<=3.4: max err ~1.3e-3 (loose 1.7e-2 tol)
__device__ __forceinline__ float tanhP(float x) {
  float t = fminf(fmaxf(x, -3.4f), 3.4f);
  float s = t * t;
  float num = t * (945.0f + s * (105.0f + s));
  float den = 945.0f + s * (420.0f + 15.0f * s);
  return num * __builtin_amdgcn_rcpf(den);
}
__device__ __forceinline__ float sigP(float x) {
  return 0.5f + 0.5f * tanhP(0.5f * x);
}
__device__ __forceinline__ f16x8 pack8(const float4& a, const float4& b) {
  f16x8 r;
  r[0] = (_Float16)a.x; r[1] = (_Float16)a.y;
  r[2] = (_Float16)a.z; r[3] = (_Float16)a.w;
  r[4] = (_Float16)b.x; r[5] = (_Float16)b.y;
  r[6] = (_Float16)b.z; r[7] = (_Float16)b.w;
  return r;
}

// Lane-order-packed weights: for each (nb, w, g, cb) a 16x32 f16 tile stored
// so lane (q*16+l15) holds elems l15*32 + q*8 .. +7 -> one wave B-fragment =
// contiguous 1 KB, coalesced, L2-resident (1.97 MB total).
__global__ __launch_bounds__(256) void build_wb2(
    _Float16* __restrict__ Wb2, const float* __restrict__ W_iou,
    const float* __restrict__ U_iou, const float* __restrict__ U_f_w) {
  int idx = blockIdx.x * 256 + threadIdx.x;  // grid covers 1280*768 exactly
  int within = idx & 511;                    // l15*32 + kk
  int blk = idx >> 9;                        // ((nb*4+w)*5 + g)*24 + cb
  int l15 = within >> 5;
  int kk = within & 31;
  int cb = blk % 24;
  int t = blk / 24;
  int g = t % 5;
  int t2 = t / 5;
  int w = t2 & 3;
  int nb = t2 >> 2;
  int col = g * 256 + nb * 64 + w * 16 + l15;
  int k = cb * 32 + kk;
  float v;
  if (col < 768)
    v = (k < 256) ? W_iou[col * 256 + k] : U_iou[col * 512 + (k - 256)];
  else
    v = (k < 256) ? 0.0f : U_f_w[(col - 768) * 512 + (k - 256)];
  Wb2[idx] = (_Float16)v;
}

// x f32 -> f16 once; all levels then stage x via global_load_lds.
__global__ __launch_bounds__(256) void conv_x16(
    _Float16* __restrict__ x16, const float* __restrict__ x, int n8) {
  int i = blockIdx.x * 256 + threadIdx.x;
  if (i < n8) {
    float4 a = *(const float4*)(x + (size_t)i * 8);
    float4 b = *(const float4*)(x + (size_t)i * 8 + 4);
    *(f16x8*)(x16 + (size_t)i * 8) = pack8(a, b);
  }
}

// ============ unified all-STAGE level kernel (x16 + h16/c16 ws) ============
// Block tile 64 rows x 64 n (x NG groups); 4 waves; wave w owns all 64 rows
// for n = nb*64 + w*16 + l15 -> wave-local epilogue.
// A-staging: EVERY chunk via global_load_lds (x16 for k<256 / leaf, hws for
// h-part), linear LDS dest + inverse-swizzled per-lane source (rule 21).
// 4-buffer rotation, ONE barrier per chunk-PAIR: stage c+2,c+3 at pair top
// (buffers retired at previous barrier), COMP(c), COMP(c+1), sync -> each
// stage overlaps 2 COMPs (~600-800cy ~ HBM latency); half the vmcnt drains.
// f-gate groups (g=3,4) skipped for chunks<4 (zero Wb2 block).
// B: register ping-pong from lane-packed Wb2 (L2-resident, never LDS).
// Epilogue: padded [64][68] f32 LDS tiles; c-inputs direct-coalesced; Pade.
// NOTE: min-waves stays 2 (R6: 3 -> scratch spill). NOTE: per-block n-split
// is load-bearing (R9: full-width block = 2 MB of B through one CU).
template <bool LEAF>
__global__ __launch_bounds__(256, 2) void level16_kernel(
    const _Float16* __restrict__ x16, const float* __restrict__ c0in,
    const _Float16* __restrict__ Wb2, const float* __restrict__ b_iou,
    const float* __restrict__ U_f_b, float* __restrict__ out,
    _Float16* __restrict__ cws, _Float16* __restrict__ hws, int m, int off,
    int coff) {
  constexpr int NG = LEAF ? 3 : 5;
  constexpr int NCH = LEAF ? 4 : 12;
  constexpr int NBU = NG * 2;
  __shared__ __align__(16) char smem[34816];  // main: 4x8KB bufs; epi: tiles
  f16x8* sA = (f16x8*)smem;

  const int tid = threadIdx.x;
  const int w = tid >> 6;
  const int lane = tid & 63;
  const int l15 = lane & 15;
  const int q = lane >> 4;

  int bx = blockIdx.x, r, nb;
  if ((gridDim.x & 31) == 0) {  // XCD-grouped: nb-splits share bid%8
    nb = (bx >> 3) & 3;
    r = ((bx >> 5) << 3) + (bx & 7);
  } else {
    r = bx >> 2;
    nb = bx & 3;
  }
  const int pbase = r << 6;
  const int arow = tid >> 3;
  const int akc = tid & 7;
  const int ku = akc ^ (arow & 7);  // same for rows arow and arow+32

  int prowA = pbase + arow;
  if (prowA >= m) prowA = pbase;
  int prowB = pbase + arow + 32;
  if (prowB >= m) prowB = pbase;

  const _Float16* bb =
      Wb2 + (size_t)(nb * 4 + w) * (5 * 24 * 512) + l15 * 32 + q * 8;

  f32x4 acc[NG][4] = {};

  auto STAGE = [&](int c, int buf) {
#pragma unroll
    for (int j = 0; j < 2; ++j) {
      const int prow = j ? prowB : prowA;
      const _Float16* src;
      if (LEAF || c < 4) {
        src = x16 + ((size_t)(off + prow) << 8) + (c << 6) + (ku << 3);
      } else {
        const int kk = ((c - 4) << 6) + (ku << 3);
        src = hws + ((size_t)(coff + 2 * prow + (kk >> 8)) << 8) + (kk & 255);
      }
      __builtin_amdgcn_global_load_lds(
          (const __attribute__((address_space(1))) void*)src,
          (__attribute__((address_space(3))) void*)(sA + (buf << 9) +
                                                    (j << 8) + tid),
          16, 0, 0);
    }
  };
  auto LOADBn = [&](f16x8 (&bv)[NBU], int c, int nbu) {
#pragma unroll
    for (int j = 0; j < NBU; ++j)
      if (j < nbu)
        bv[j] = *(const f16x8*)(bb + (((j >> 1) * 24 + c * 2 + (j & 1)) << 9));
  };
  auto COMP = [&](int buf, f16x8 (&bv)[NBU], int ng) {
#pragma unroll
    for (int ks = 0; ks < 2; ++ks) {
      f16x8 af[4];
#pragma unroll
      for (int rf = 0; rf < 4; ++rf) {
        const int rowr = rf * 16 + l15;
        af[rf] = sA[(buf << 9) | (rowr << 3) | ((ks * 4 + q) ^ (rowr & 7))];
      }
#pragma unroll
      for (int g = 0; g < NG; ++g)
        if (g < ng) {
          const f16x8 bf = bv[g * 2 + ks];
#pragma unroll
          for (int rf = 0; rf < 4; ++rf)
            acc[g][rf] = __builtin_amdgcn_mfma_f32_16x16x32_f16(
                af[rf], bf, acc[g][rf], 0, 0, 0);
        }
    }
  };

  f16x8 bv0[NBU], bv1[NBU];
  STAGE(0, 0);
  LOADBn(bv0, 0, 6);
  STAGE(1, 1);
  LOADBn(bv1, 1, 6);
  __syncthreads();

#pragma unroll
  for (int p = 0; p < NCH / 2; ++p) {
    const int c = 2 * p;
    if (c + 2 < NCH) {
      STAGE(c + 2, (c + 2) & 3);
      STAGE(c + 3, (c + 3) & 3);
    }
    COMP(c & 3, bv0, (LEAF || c < 4) ? 3 : 5);
    if (c + 2 < NCH) LOADBn(bv0, c + 2, (LEAF || c + 2 < 4) ? 6 : 10);
    COMP((c + 1) & 3, bv1, (LEAF || c + 1 < 4) ? 3 : 5);
    if (c + 3 < NCH) LOADBn(bv1, c + 3, (LEAF || c + 3 < 4) ? 6 : 10);
    __syncthreads();  // retires this pair's reads; drains stages of c+2,c+3
  }

  // ===== epilogue: padded-tile transpose, all global I/O coalesced ========
  const int erow = tid >> 2;
  const int eseg = tid & 3;
  const int p_e = pbase + erow;
  const bool pv = p_e < m;
  float* T0 = (float*)smem;  // [64][68] f32
  float* T1 = T0 + 64 * 68;
  const int scol = (w << 4) + l15;
  const int n = (nb << 6) + scol;
  const int rbase = erow * 68 + (eseg << 4);

  float cred[16];
  if constexpr (!LEAF) {
    float c0v[16], c1v[16];
    if (pv) {
      const _Float16* csrc =
          cws + (size_t)(coff + 2 * p_e) * 256 + (nb << 6) + (eseg << 4);
      f16x8 a0 = *(const f16x8*)csrc;
      f16x8 a1 = *(const f16x8*)(csrc + 8);
      f16x8 b0 = *(const f16x8*)(csrc + 256);
      f16x8 b1 = *(const f16x8*)(csrc + 264);
#pragma unroll
      for (int j = 0; j < 8; ++j) {
        c0v[j] = (float)a0[j]; c0v[8 + j] = (float)a1[j];
        c1v[j] = (float)b0[j]; c1v[8 + j] = (float)b1[j];
      }
    } else {
#pragma unroll
      for (int j = 0; j < 16; ++j) { c0v[j] = 0.f; c1v[j] = 0.f; }
    }
    const float bf0 = U_f_b[n], bf1 = U_f_b[256 + n];
#pragma unroll
    for (int rf = 0; rf < 4; ++rf)
#pragma unroll
      for (int rr = 0; rr < 4; ++rr) {
        const int prow = rf * 16 + (q << 2) + rr;
        T0[prow * 68 + scol] = sigP(acc[3][rf][rr] + bf0);
        T1[prow * 68 + scol] = sigP(acc[4][rf][rr] + bf1);
      }
    __syncthreads();
#pragma unroll
    for (int jj = 0; jj < 4; ++jj) {
      float4 f04 = *(const float4*)&T0[rbase + jj * 4];
      float4 f14 = *(const float4*)&T1[rbase + jj * 4];
      cred[jj * 4 + 0] = f04.x * c0v[jj * 4 + 0] + f14.x * c1v[jj * 4 + 0];
      cred[jj * 4 + 1] = f04.y * c0v[jj * 4 + 1] + f14.y * c1v[jj * 4 + 1];
      cred[jj * 4 + 2] = f04.z * c0v[jj * 4 + 2] + f14.z * c1v[jj * 4 + 2];
      cred[jj * 4 + 3] = f04.w * c0v[jj * 4 + 3] + f14.w * c1v[jj * 4 + 3];
    }
    __syncthreads();
  } else {
    if (pv) {
      const float* src =
          c0in + (size_t)(off + p_e) * 256 + (nb << 6) + (eseg << 4);
#pragma unroll
      for (int jj = 0; jj < 4; ++jj) {
        float4 v = *(const float4*)(src + jj * 4);
        cred[jj * 4 + 0] = v.x; cred[jj * 4 + 1] = v.y;
        cred[jj * 4 + 2] = v.z; cred[jj * 4 + 3] = v.w;
      }
    } else {
#pragma unroll
      for (int j = 0; j < 16; ++j) cred[j] = 0.f;
    }
  }

  {
    const float bi = b_iou[n], bo = b_iou[256 + n], bu = b_iou[512 + n];
#pragma unroll
    for (int rf = 0; rf < 4; ++rf)
#pragma unroll
      for (int rr = 0; rr < 4; ++rr) {
        const int prow = rf * 16 + (q << 2) + rr;
        const float iv = sigP(acc[0][rf][rr] + bi);
        const float uv = tanhP(acc[2][rf][rr] + bu);
        const float ov = sigP(acc[1][rf][rr] + bo);
        T0[prow * 68 + scol] = iv * uv;
        T1[prow * 68 + scol] = ov;
      }
  }
  __syncthreads();

  if (pv) {
    float4 h4[4], c4[4];
#pragma unroll
    for (int jj = 0; jj < 4; ++jj) {
      float4 iu4 = *(const float4*)&T0[rbase + jj * 4];
      float4 o4 = *(const float4*)&T1[rbase + jj * 4];
      float cc;
      cc = iu4.x + cred[jj * 4 + 0]; c4[jj].x = cc; h4[jj].x = o4.x * tanhP(cc);
      cc = iu4.y + cred[jj * 4 + 1]; c4[jj].y = cc; h4[jj].y = o4.y * tanhP(cc);
      cc = iu4.z + cred[jj * 4 + 2]; c4[jj].z = cc; h4[jj].z = o4.z * tanhP(cc);
      cc = iu4.w + cred[jj * 4 + 3]; c4[jj].w = cc; h4[jj].w = o4.w * tanhP(cc);
    }
    const size_t ob = (size_t)(off + p_e) * 256 + (nb << 6) + (eseg << 4);
    float* dst = out + ob;
#pragma unroll
    for (int jj = 0; jj < 4; ++jj) *(float4*)(dst + jj * 4) = h4[jj];
    *(f16x8*)(hws + ob) = pack8(h4[0], h4[1]);
    *(f16x8*)(hws + ob + 8) = pack8(h4[2], h4[3]);
    *(f16x8*)(cws + ob) = pack8(c4[0], c4[1]);
    *(f16x8*)(cws + ob + 8) = pack8(c4[2], c4[3]);
  }
}

// ==================== R12 fallback (no x16 workspace) ======================
template <bool LEAF, bool H16, typename CT>
__device__ __forceinline__ void level_body(
    const float* __restrict__ x, const float* __restrict__ c0in,
    const _Float16* __restrict__ Wb2, const float* __restrict__ b_iou,
    const float* __restrict__ U_f_b, float* __restrict__ out,
    CT* __restrict__ cws, _Float16* __restrict__ hws, int m, int off,
    int coff, int r, int nb) {
  constexpr int NG = LEAF ? 3 : 5;
  constexpr int NCH = LEAF ? 4 : 12;
  constexpr int NBU = NG * 2;
  __shared__ __align__(16) char smem[34816];
  f16x8* sA = (f16x8*)smem;

  const int tid = threadIdx.x;
  const int w = tid >> 6;
  const int lane = tid & 63;
  const int l15 = lane & 15;
  const int q = lane >> 4;
  const int pbase = r << 6;
  const int arow = tid >> 3;
  const int akc = tid & 7;

  const _Float16* bb =
      Wb2 + (size_t)(nb * 4 + w) * (5 * 24 * 512) + l15 * 32 + q * 8;

  f32x4 acc[NG][4] = {};

  auto LOADA = [&](float4 (&ax)[2][2], f16x8 (&ah)[2], int c) {
    const int k0 = (c << 6) + (akc << 3);
#pragma unroll
    for (int j = 0; j < 2; ++j) {
      const int row = arow + j * 32;
      const int p = pbase + row;
      const bool xpart = LEAF || c < 4;
      if (p < m) {
        if (xpart) {
          const float* src = x + (size_t)(off + p) * 256 + k0;
          ax[j][0] = *(const float4*)src;
          ax[j][1] = *(const float4*)(src + 4);
        } else if (H16) {
          ah[j] = *(const f16x8*)(hws + (size_t)(coff + 2 * p) * 256 +
                                  (k0 - 256));
        } else {
          const float* src = out + (size_t)(coff + 2 * p) * 256 + (k0 - 256);
          ax[j][0] = *(const float4*)src;
          ax[j][1] = *(const float4*)(src + 4);
        }
      } else {
        ax[j][0] = float4{0.f, 0.f, 0.f, 0.f};
        ax[j][1] = float4{0.f, 0.f, 0.f, 0.f};
        f16x8 z = {};
        ah[j] = z;
      }
    }
  };
  auto WRITEA = [&](float4 (&ax)[2][2], f16x8 (&ah)[2], int c) {
#pragma unroll
    for (int j = 0; j < 2; ++j) {
      const int row = arow + j * 32;
      f16x8 v;
      if (H16 && !LEAF && c >= 4) v = ah[j];
      else v = pack8(ax[j][0], ax[j][1]);
      sA[((c & 1) << 9) | (row << 3) | (akc ^ (row & 7))] = v;
    }
  };
  auto LOADB = [&](f16x8 (&bv)[NBU], int c) {
#pragma unroll
    for (int j = 0; j < NBU; ++j)
      bv[j] = *(const f16x8*)(bb + (((j >> 1) * 24 + c * 2 + (j & 1)) << 9));
  };
  auto COMPUTE = [&](int buf, f16x8 (&bv)[NBU]) {
#pragma unroll
    for (int ks = 0; ks < 2; ++ks) {
      f16x8 af[4];
#pragma unroll
      for (int rf = 0; rf < 4; ++rf) {
        const int row = rf * 16 + l15;
        af[rf] = sA[(buf << 9) | (row << 3) | ((ks * 4 + q) ^ (row & 7))];
      }
#pragma unroll
      for (int g = 0; g < NG; ++g) {
        const f16x8 bf = bv[g * 2 + ks];
#pragma unroll
        for (int rf = 0; rf < 4; ++rf)
          acc[g][rf] = __builtin_amdgcn_mfma_f32_16x16x32_f16(
              af[rf], bf, acc[g][rf], 0, 0, 0);
      }
    }
  };

  float4 axA[2][2], axB[2][2];
  f16x8 ahA[2], ahB[2];
  f16x8 bvA[NBU], bvB[NBU];

  LOADA(axA, ahA, 0);
  LOADB(bvA, 0);
  WRITEA(axA, ahA, 0);
  LOADA(axB, ahB, 1);
  LOADB(bvB, 1);
  __syncthreads();

  for (int c = 0; c < NCH; c += 2) {
    if (c + 2 < NCH) LOADA(axA, ahA, c + 2);
    COMPUTE(0, bvA);
    WRITEA(axB, ahB, c + 1);
    if (c + 2 < NCH) LOADB(bvA, c + 2);
    __syncthreads();
    if (c + 3 < NCH) LOADA(axB, ahB, c + 3);
    COMPUTE(1, bvB);
    if (c + 2 < NCH) {
      WRITEA(axA, ahA, c + 2);
      if (c + 3 < NCH) LOADB(bvB, c + 3);
      __syncthreads();
    }
  }
  __syncthreads();

  const int erow = tid >> 2;
  const int eseg = tid & 3;
  const int p_e = pbase + erow;
  const bool pv = p_e < m;
  float* T0 = (float*)smem;
  float* T1 = T0 + 64 * 68;
  const int scol = (w << 4) + l15;
  const int n = (nb << 6) + scol;
  const int rbase = erow * 68 + (eseg << 4);

  float cred[16];
  if constexpr (!LEAF) {
    float c0v[16], c1v[16];
    if (pv) {
      const CT* csrc =
          cws + (size_t)(coff + 2 * p_e) * 256 + (nb << 6) + (eseg << 4);
      if constexpr (sizeof(CT) == 2) {
        f16x8 a0 = *(const f16x8*)csrc;
        f16x8 a1 = *(const f16x8*)(csrc + 8);
        f16x8 b0 = *(const f16x8*)(csrc + 256);
        f16x8 b1 = *(const f16x8*)(csrc + 264);
#pragma unroll
        for (int j = 0; j < 8; ++j) {
          c0v[j] = (float)a0[j]; c0v[8 + j] = (float)a1[j];
          c1v[j] = (float)b0[j]; c1v[8 + j] = (float)b1[j];
        }
      } else {
#pragma unroll
        for (int jj = 0; jj < 4; ++jj) {
          float4 v0 = *(const float4*)((const float*)csrc + jj * 4);
          float4 v1 = *(const float4*)((const float*)csrc + 256 + jj * 4);
          c0v[jj * 4 + 0] = v0.x; c0v[jj * 4 + 1] = v0.y;
          c0v[jj * 4 + 2] = v0.z; c0v[jj * 4 + 3] = v0.w;
          c1v[jj * 4 + 0] = v1.x; c1v[jj * 4 + 1] = v1.y;
          c1v[jj * 4 + 2] = v1.z; c1v[jj * 4 + 3] = v1.w;
        }
      }
    } else {
#pragma unroll
      for (int j = 0; j < 16; ++j) { c0v[j] = 0.f; c1v[j] = 0.f; }
    }
    const float bf0 = U_f_b[n], bf1 = U_f_b[256 + n];
#pragma unroll
    for (int rf = 0; rf < 4; ++rf)
#pragma unroll
      for (int rr = 0; rr < 4; ++rr) {
        const int prow = rf * 16 + (q << 2) + rr;
        T0[prow * 68 + scol] = sigP(acc[3][rf][rr] + bf0);
        T1[prow * 68 + scol] = sigP(acc[4][rf][rr] + bf1);
      }
    __syncthreads();
#pragma unroll
    for (int jj = 0; jj < 4; ++jj) {
      float4 f04 = *(const float4*)&T0[rbase + jj * 4];
      float4 f14 = *(const float4*)&T1[rbase + jj * 4];
      cred[jj * 4 + 0] = f04.x * c0v[jj * 4 + 0] + f14.x * c1v[jj * 4 + 0];
      cred[jj * 4 + 1] = f04.y * c0v[jj * 4 + 1] + f14.y * c1v[jj * 4 + 1];
      cred[jj * 4 + 2] = f04.z * c0v[jj * 4 + 2] + f14.z * c1v[jj * 4 + 2];
      cred[jj * 4 + 3] = f04.w * c0v[jj * 4 + 3] + f14.w * c1v[jj * 4 + 3];
    }
    __syncthreads();
  } else {
    if (pv) {
      const float* src =
          c0in + (size_t)(off + p_e) * 256 + (nb << 6) + (eseg << 4);
#pragma unroll
      for (int jj = 0; jj < 4; ++jj) {
        float4 v = *(const float4*)(src + jj * 4);
        cred[jj * 4 + 0] = v.x; cred[jj * 4 + 1] = v.y;
        cred[jj * 4 + 2] = v.z; cred[jj * 4 + 3] = v.w;
      }
    } else {
#pragma unroll
      for (int j = 0; j < 16; ++j) cred[j] = 0.f;
    }
  }

  {
    const float bi = b_iou[n], bo = b_iou[256 + n], bu = b_iou[512 + n];
#pragma unroll
    for (int rf = 0; rf < 4; ++rf)
#pragma unroll
      for (int rr = 0; rr < 4; ++rr) {
        const int prow = rf * 16 + (q << 2) + rr;
        const float iv = sigP(acc[0][rf][rr] + bi);
        const float uv = tanhP(acc[2][rf][rr] + bu);
        const float ov = sigP(acc[1][rf][rr] + bo);
        T0[prow * 68 + scol] = iv * uv;
        T1[prow * 68 + scol] = ov;
      }
  }
  __syncthreads();

  if (pv) {
    float4 h4[4], c4[4];
#pragma unroll
    for (int jj = 0; jj < 4; ++jj) {
      float4 iu4 = *(const float4*)&T0[rbase + jj * 4];
      float4 o4 = *(const float4*)&T1[rbase + jj * 4];
      float cc;
      cc = iu4.x + cred[jj * 4 + 0]; c4[jj].x = cc; h4[jj].x = o4.x * tanhP(cc);
      cc = iu4.y + cred[jj * 4 + 1]; c4[jj].y = cc; h4[jj].y = o4.y * tanhP(cc);
      cc = iu4.z + cred[jj * 4 + 2]; c4[jj].z = cc; h4[jj].z = o4.z * tanhP(cc);
      cc = iu4.w + cred[jj * 4 + 3]; c4[jj].w = cc; h4[jj].w = o4.w * tanhP(cc);
    }
    const size_t ob = (size_t)(off + p_e) * 256 + (nb << 6) + (eseg << 4);
    float* dst = out + ob;
#pragma unroll
    for (int jj = 0; jj < 4; ++jj) *(float4*)(dst + jj * 4) = h4[jj];
    if constexpr (H16) {
      *(f16x8*)(hws + ob) = pack8(h4[0], h4[1]);
      *(f16x8*)(hws + ob + 8) = pack8(h4[2], h4[3]);
    }
    if constexpr (sizeof(CT) == 2) {
      *(f16x8*)((_Float16*)cws + ob) = pack8(c4[0], c4[1]);
      *(f16x8*)((_Float16*)cws + ob + 8) = pack8(c4[2], c4[3]);
    } else {
      float* cdst = (float*)cws + ob;
#pragma unroll
      for (int jj = 0; jj < 4; ++jj) *(float4*)(cdst + jj * 4) = c4[jj];
    }
  }
}

template <bool LEAF, bool H16, typename CT>
__global__ __launch_bounds__(256, 2) void level_kernel(
    const float* __restrict__ x, const float* __restrict__ c0in,
    const _Float16* __restrict__ Wb2, const float* __restrict__ b_iou,
    const float* __restrict__ U_f_b, float* __restrict__ out,
    CT* __restrict__ cws, _Float16* __restrict__ hws, int m, int off,
    int coff) {
  int bx = blockIdx.x, r, nb;
  if ((gridDim.x & 31) == 0) {
    nb = (bx >> 3) & 3;
    r = ((bx >> 5) << 3) + (bx & 7);
  } else {
    r = bx >> 2;
    nb = bx & 3;
  }
  level_body<LEAF, H16, CT>(x, c0in, Wb2, b_iou, U_f_b, out, cws, hws, m, off,
                            coff, r, nb);
}

// ============================== dispatch ===================================
template <bool H16, typename CT>
static void run_levels(const float* x, const float* c0, const _Float16* Wb2,
                       const float* b_iou, const float* U_f_b, float* out,
                       CT* cws, _Float16* hws, hipStream_t stream) {
  level_kernel<true, H16, CT><<<dim3(4096), 256, 0, stream>>>(
      x, c0, Wb2, b_iou, U_f_b, out, cws, hws, 65536, 65535, 0);
  for (int k = DEPTH - 2; k >= 0; --k) {
    const int m = 1 << k;
    const int R = (m + 63) / 64;
    level_kernel<false, H16, CT><<<dim3(R * 4), 256, 0, stream>>>(
        x, c0, Wb2, b_iou, U_f_b, out, cws, hws, m, m - 1, 2 * m - 1);
  }
}

extern "C" void kernel_launch(void* const* d_in, const int* in_sizes, int n_in,
                              void* d_out, int out_size, void* d_ws, size_t ws_size,
                              hipStream_t stream) {
  const float* x     = (const float*)d_in[0];
  // d_in[1] = h0 (unused by the reference's math)
  const float* c0    = (const float*)d_in[2];
  const float* W_iou = (const float*)d_in[3];
  const float* U_iou = (const float*)d_in[4];
  const float* b_iou = (const float*)d_in[5];
  const float* U_f_w = (const float*)d_in[6];
  const float* U_f_b = (const float*)d_in[7];
  float* out = (float*)d_out;

  char* ws = (char*)d_ws;
  const size_t wbBytes = (size_t)1280 * 768 * 2;  // 1.97 MB, 16B-aligned
  _Float16* Wb2 = (_Float16*)ws;
  build_wb2<<<3840, 256, 0, stream>>>(Wb2, W_iou, U_iou, U_f_w);

  const size_t cElems = (size_t)NNODES * 256;  // 33.55M
  char* p1 = ws + wbBytes;
  if (ws_size >= wbBytes + cElems * 2 * 3) {
    // tiers: [c16][h16][x16]
    _Float16* cws = (_Float16*)p1;
    _Float16* hws = (_Float16*)(p1 + cElems * 2);
    _Float16* x16 = (_Float16*)(p1 + cElems * 4);
    const int n8 = (int)(cElems / 8);
    conv_x16<<<dim3((n8 + 255) / 256), 256, 0, stream>>>(x16, x, n8);
    level16_kernel<true><<<dim3(4096), 256, 0, stream>>>(
        x16, c0, Wb2, b_iou, U_f_b, out, cws, hws, 65536, 65535, 0);
    for (int k = DEPTH - 2; k >= 0; --k) {
      const int m = 1 << k;
      const int R = (m + 63) / 64;
      level16_kernel<false><<<dim3(R * 4), 256, 0, stream>>>(
          x16, c0, Wb2, b_iou, U_f_b, out, cws, hws, m, m - 1, 2 * m - 1);
    }
  } else if (ws_size >= wbBytes + cElems * 2 + cElems * 2) {
    run_levels<true, _Float16>(x, c0, Wb2, b_iou, U_f_b, out, (_Float16*)p1,
                               (_Float16*)(p1 + cElems * 2), stream);
  } else if (ws_size >= wbBytes + cElems * 4) {
    run_levels<false, float>(x, c0, Wb2, b_iou, U_f_b, out, (float*)p1,
                             nullptr, stream);
  } else {
    run_levels<false, _Float16>(x, c0, Wb2, b_iou, U_f_b, out, (_Float16*)p1,
                                nullptr, stream);
  }
}